// Round 10
// baseline (4422.515 us; speedup 1.0000x reference)
//
#include <hip/hip_runtime.h>
#include <math.h>

#define B_   8
#define N_   2048
#define K_   16
#define C2_  128
#define C4_  256
#define KH_  8
#define TAP_ 9
#define NK_  32768
#define EPSv 1e-5f
#define BIGF 3.0e38f
#define NMASK 2047

constexpr size_t AL(size_t x) { return (x + 255) & ~(size_t)255; }
constexpr size_t OFF_XT   = 0;                                                  // f32 [B][N][64]
constexpr size_t OFF_IDX  = OFF_XT  + AL(4ull * B_ * N_ * 64);                  // int [B][N][16]
constexpr size_t OFF_U1   = OFF_IDX + AL(4ull * B_ * N_ * K_);
constexpr size_t OFF_V1   = OFF_U1  + AL(4ull * B_ * 16 * N_);
constexpr size_t OFF_U2   = OFF_V1  + AL(4ull * B_ * N_ * 16);
constexpr size_t OFF_V2   = OFF_U2  + AL(4ull * B_ * 16 * N_);
constexpr size_t OFF_S    = OFF_V2  + AL(4ull * B_ * N_ * 16);                  // f32 [B][N][128]
constexpr size_t OFF_P    = OFF_S   + AL(4ull * B_ * N_ * C2_);                 // f32 [B][N][256]
constexpr size_t OFF_W1   = OFF_P   + AL(4ull * B_ * N_ * C4_);                 // f32 [B][16][NK]
constexpr size_t OFF_QB   = OFF_W1  + AL(4ull * B_ * 16 * NK_);                 // f32 [B][N][9][256]
constexpr size_t OFF_ITB  = OFF_QB  + AL(4ull * (size_t)B_ * N_ * TAP_ * C4_);  // f32 [B][N][2048] (o*8+j)
constexpr size_t OFF_A4B  = OFF_ITB + AL(4ull * (size_t)B_ * N_ * 2048);        // f32 [B][N][2048] (cc*16+kk)
constexpr size_t OFF_PART = OFF_A4B + AL(4ull * (size_t)B_ * N_ * 2048);        // f32 [4][B][N][128]
constexpr size_t OFF_OUT2 = OFF_PART+ AL(4ull * 4 * (size_t)B_ * N_ * C2_);     // f32 [B][N][128]
constexpr size_t OFF_WQ2  = OFF_OUT2+ AL(4ull * B_ * N_ * C2_);
constexpr size_t OFF_WC2  = OFF_WQ2 + AL(4ull * TAP_ * C4_ * 64);
constexpr size_t OFF_WP2  = OFF_WC2 + AL(4ull * 3072 * C2_);
constexpr size_t OFF_WS2  = OFF_WP2 + AL(4ull * C4_ * 64);
constexpr size_t OFF_WU12 = OFF_WS2 + AL(4ull * C2_ * 64);
constexpr size_t OFF_WV12 = OFF_WU12+ AL(4ull * 16 * 64);
constexpr size_t OFF_WU22 = OFF_WV12+ AL(4ull * 16 * 64);
constexpr size_t OFF_WV22 = OFF_WU22+ AL(4ull * 64);
constexpr size_t OFF_A12  = OFF_WV22+ AL(4ull * 64);
constexpr size_t OFF_A22  = OFF_A12 + AL(4ull * 64 * 16);
constexpr size_t OFF_ST   = OFF_A22 + AL(4ull * C2_ * 64);
constexpr size_t OFF_PROG = OFF_ST  + AL(4ull * 4096);
constexpr size_t POOL_SZ  = OFF_PROG + AL(4ull * 64);

static char* g_pool_mem = nullptr;
struct PoolInit {
  PoolInit() { if (hipMalloc((void**)&g_pool_mem, POOL_SZ) != hipSuccess) g_pool_mem = nullptr; }
};
static PoolInit g_pool_init;

// g_st float offsets
#define ST_S1S 0
#define ST_S1Q 16
#define ST_S2S 32
#define ST_S2Q 48
#define ST_S5S 64
#define ST_S5Q 320
#define ST_S4S 576
#define ST_S4Q 704
#define ST_S6S 832
#define ST_S6Q 960
#define ST_B1SC 1088
#define ST_B1SH 1104
#define ST_B2SC 1120
#define ST_B2SH 1136
#define ST_B3SC 1152
#define ST_B3SH 1216
#define ST_B4SC 1280
#define ST_B4SH 1408
#define ST_B5SC 1536
#define ST_B5SH 1792
#define ST_B6SC 2048
#define ST_B6SH 2176
#define ST_S3M  2304
#define ST_S3V  2440

#define BASE(b)  char* bb = (b)
#define P_XT   ((float*)(bb + OFF_XT))
#define P_IDX  ((int*)(bb + OFF_IDX))
#define P_U1   ((float*)(bb + OFF_U1))
#define P_V1   ((float*)(bb + OFF_V1))
#define P_U2   ((float*)(bb + OFF_U2))
#define P_V2   ((float*)(bb + OFF_V2))
#define P_Sb   ((float*)(bb + OFF_S))
#define P_P    ((float*)(bb + OFF_P))
#define P_W1   ((float*)(bb + OFF_W1))
#define P_QB   ((float*)(bb + OFF_QB))
#define P_IT   ((float*)(bb + OFF_ITB))
#define P_A4   ((float*)(bb + OFF_A4B))
#define P_PART ((float*)(bb + OFF_PART))
#define P_OUT2 ((float*)(bb + OFF_OUT2))
#define P_WQ2  ((float*)(bb + OFF_WQ2))
#define P_WC2  ((float*)(bb + OFF_WC2))
#define P_WP2  ((float*)(bb + OFF_WP2))
#define P_WS2  ((float*)(bb + OFF_WS2))
#define P_WU12 ((float*)(bb + OFF_WU12))
#define P_WV12 ((float*)(bb + OFF_WV12))
#define P_WU22 ((float*)(bb + OFF_WU22))
#define P_WV22 ((float*)(bb + OFF_WV22))
#define P_A12  ((float*)(bb + OFF_A12))
#define P_A22  ((float*)(bb + OFF_A22))
#define P_ST   ((float*)(bb + OFF_ST))
#define P_PROG ((int*)(bb + OFF_PROG))

#define PROG(id) do { if (threadIdx.x == 0) atomicAdd(&P_PROG[(id)], 1); } while (0)

static __device__ __forceinline__ float lrelu(float x) { return x >= 0.0f ? x : 0.01f * x; }

// --------------------------------------------------------------------------- id 0
__global__ __launch_bounds__(256) void zero_kernel(char* base)
{
  BASE(base);
  for (int i = threadIdx.x; i < 4096; i += 256) P_ST[i] = 0.0f;
  for (int i = threadIdx.x; i < 64; i += 256) P_PROG[i] = 0;
  __syncthreads();
  if (threadIdx.x == 0) P_PROG[0] = 1;
}

// --------------------------------------------------------------------------- id 1
__global__ __launch_bounds__(256) void prep_kernel(char* base,
    const float* __restrict__ x, const float* __restrict__ fea_w,
    const float* __restrict__ xyz_w, const float* __restrict__ inte_w,
    const float* __restrict__ c2_w, const float* __restrict__ all1_w,
    const float* __restrict__ all2_w)
{
  BASE(base);
  PROG(1);
  int i = blockIdx.x * 256 + threadIdx.x;
  if (i < 1048576) {                       // xT[b][m][c] = x[b][c][m]
    int c = i & 63; int m = (i >> 6) & 2047; int b = i >> 17;
    P_XT[i] = x[((size_t)(b * 64 + c)) * N_ + m];
    return;
  }
  i -= 1048576;
  if (i < 1024) { int c = i & 63, o = i >> 6;
    P_WU12[i] = fea_w[o * 128 + c] - fea_w[o * 128 + 64 + c]; return; }
  i -= 1024;
  if (i < 1024) { int c = i & 63, o = i >> 6;
    P_WV12[i] = fea_w[o * 128 + 64 + c]; return; }
  i -= 1024;
  if (i < 64) { int c = i & 3, o = i >> 2;
    P_WU22[i] = (c < 3) ? (xyz_w[o * 6 + c] - xyz_w[o * 6 + 3 + c]) : 0.0f; return; }
  i -= 64;
  if (i < 64) { int c = i & 3, o = i >> 2;
    P_WV22[i] = (c < 3) ? xyz_w[o * 6 + 3 + c] : 0.0f; return; }
  i -= 64;
  if (i < 16384) { int c = i & 63, o = i >> 6;
    float s = 0.0f;
    for (int t = 0; t < TAP_; t++)
      s += inte_w[(o * 128 + c) * TAP_ + t] - inte_w[(o * 128 + 64 + c) * TAP_ + t];
    P_WP2[i] = s; return; }
  i -= 16384;
  if (i < 147456) { int c = i & 63; int to = i >> 6; int o = to & 255; int tt = to >> 8;
    P_WQ2[i] = inte_w[(o * 128 + 64 + c) * TAP_ + tt]; return; }
  i -= 147456;
  if (i < 8192) { int c = i & 63, o = i >> 6;
    float s = 0.0f;
    for (int p = 0; p < 16; p++)
      s += c2_w[(o * 128 + c) * 32 + p] - c2_w[(o * 128 + 64 + c) * 32 + p];
    P_WS2[i] = s; return; }
  i -= 8192;
  if (i < 393216) { int o = i & 127; int k = i >> 7; float v;
    if (k < 1024) { int c = k >> 4, p = k & 15; v = c2_w[(o * 128 + 64 + c) * 32 + p]; }
    else { int kr = k - 1024; int cc = kr >> 4, kk = kr & 15; v = c2_w[(o * 128 + cc) * 32 + 16 + kk]; }
    P_WC2[i] = v; return; }
  i -= 393216;
  if (i < 1024) { int c = i & 15, o = i >> 4; P_A12[i] = all1_w[o * 16 + c]; return; }
  i -= 1024;
  if (i < 8192) { int c = i & 63, o = i >> 6; P_A22[i] = all2_w[o * 64 + c]; return; }
}

// --------------------------------------------------------------------------- id 2
__global__ __launch_bounds__(256) void knn_kernel(char* base)
{
  BASE(base);
  PROG(2);
  int b = blockIdx.x >> 9; int n0 = (blockIdx.x & 511) * 4;
  int t = threadIdx.x;
  __shared__ float sdist[4][N_];
  __shared__ __align__(16) float xn[4][64];
  __shared__ float sxn[4];
  {
    int nn = t >> 6, c = t & 63;
    xn[nn][c] = P_XT[((size_t)(b * N_) + n0 + nn) * 64 + c];
  }
  __syncthreads();
  if (t < 4) {
    float s = 0.0f;
    for (int c = 0; c < 64; c++) { float v = xn[t][c]; s += v * v; }
    sxn[t] = s;
  }
  __syncthreads();
  float dd[32]; float xs[8];
#pragma unroll
  for (int i = 0; i < 32; i++) dd[i] = 0.0f;
#pragma unroll
  for (int i = 0; i < 8; i++) xs[i] = 0.0f;
  for (int cq = 0; cq < 16; cq++) {
    float4 a0 = *(const float4*)&xn[0][cq * 4];
    float4 a1 = *(const float4*)&xn[1][cq * 4];
    float4 a2 = *(const float4*)&xn[2][cq * 4];
    float4 a3 = *(const float4*)&xn[3][cq * 4];
#pragma unroll
    for (int mi = 0; mi < 8; mi++) {
      const float4 xv = *(const float4*)&P_XT[((size_t)(b * N_) + t + mi * 256) * 64 + cq * 4];
      xs[mi] += xv.x * xv.x + xv.y * xv.y + xv.z * xv.z + xv.w * xv.w;
      dd[0 * 8 + mi] += a0.x * xv.x + a0.y * xv.y + a0.z * xv.z + a0.w * xv.w;
      dd[1 * 8 + mi] += a1.x * xv.x + a1.y * xv.y + a1.z * xv.z + a1.w * xv.w;
      dd[2 * 8 + mi] += a2.x * xv.x + a2.y * xv.y + a2.z * xv.z + a2.w * xv.w;
      dd[3 * 8 + mi] += a3.x * xv.x + a3.y * xv.y + a3.z * xv.z + a3.w * xv.w;
    }
  }
  float sx0 = sxn[0], sx1 = sxn[1], sx2 = sxn[2], sx3 = sxn[3];
#pragma unroll
  for (int mi = 0; mi < 8; mi++) {
    int m = t + mi * 256;
    float d0 = -2.0f * dd[0 * 8 + mi] + sx0 + xs[mi];
    float d1 = -2.0f * dd[1 * 8 + mi] + sx1 + xs[mi];
    float d2 = -2.0f * dd[2 * 8 + mi] + sx2 + xs[mi];
    float d3 = -2.0f * dd[3 * 8 + mi] + sx3 + xs[mi];
    sdist[0][m] = (m == n0 + 0) ? BIGF : d0;
    sdist[1][m] = (m == n0 + 1) ? BIGF : d1;
    sdist[2][m] = (m == n0 + 2) ? BIGF : d2;
    sdist[3][m] = (m == n0 + 3) ? BIGF : d3;
  }
  __syncthreads();
  int ln = t & 63; int wv = t >> 6;
  for (int it = 0; it < K_; it++) {
    float bv = sdist[wv][ln]; int bi = ln;
    for (int mi = 1; mi < 32; mi++) {
      int m = ln + mi * 64;
      float v = sdist[wv][m];
      if (v < bv) { bv = v; bi = m; }
    }
#pragma unroll
    for (int off = 32; off > 0; off >>= 1) {
      float ov = __shfl_xor(bv, off);
      int oi = __shfl_xor(bi, off);
      if (ov < bv || (ov == bv && oi < bi)) { bv = ov; bi = oi; }
    }
    bi &= NMASK;
    if (ln == 0) {
      P_IDX[((size_t)(b * N_) + n0 + wv) * K_ + it] = bi;
      sdist[wv][bi] = BIGF;
    }
    __syncthreads();
  }
}

// --------------------------------------------------------------------------- id 3
__global__ __launch_bounds__(256) void point_gemm_kernel(char* base,
                                                         const float* __restrict__ pc)
{
  BASE(base);
  PROG(3);
  int b = blockIdx.x >> 5; int m0 = (blockIdx.x & 31) * 64;
  int t = threadIdx.x;
  __shared__ __align__(16) float xsm[64 * 68];
  __shared__ float pcs[64 * 4];
  for (int i = t; i < 4096; i += 256) {
    int c = i & 63, mm = i >> 6;
    xsm[mm * 68 + c] = P_XT[((size_t)(b * N_) + m0 + mm) * 64 + c];
  }
  if (t < 192) {
    int mm = t / 3, c = t - mm * 3;
    pcs[mm * 4 + c] = pc[(b * 3 + c) * N_ + m0 + mm];
  }
  __syncthreads();
  int mm = t & 63;
  int og = t >> 6;
  float in[64];
  for (int cq = 0; cq < 16; cq++) {
    float4 v = *(const float4*)&xsm[mm * 68 + cq * 4];
    in[cq * 4 + 0] = v.x; in[cq * 4 + 1] = v.y; in[cq * 4 + 2] = v.z; in[cq * 4 + 3] = v.w;
  }
  int m = m0 + mm;
  {
    float* pp = P_P + ((size_t)(b * N_) + m) * C4_;
    for (int oi = 0; oi < 64; oi++) {
      const float* w = P_WP2 + ((size_t)(og * 64 + oi)) * 64;
      float a = 0.0f;
#pragma unroll
      for (int c = 0; c < 64; c++) a += w[c] * in[c];
      pp[og * 64 + oi] = a;
    }
  }
  if (og < 2) {
    float* sp = P_Sb + ((size_t)(b * N_) + m) * C2_;
    for (int oi = 0; oi < 64; oi++) {
      const float* w = P_WS2 + ((size_t)(og * 64 + oi)) * 64;
      float a = 0.0f;
#pragma unroll
      for (int c = 0; c < 64; c++) a += w[c] * in[c];
      sp[og * 64 + oi] = a;
    }
  }
  if (og == 3) {
    for (int o = 0; o < 16; o++) {
      const float* w = P_WU12 + o * 64;
      float a = 0.0f;
#pragma unroll
      for (int c = 0; c < 64; c++) a += w[c] * in[c];
      P_U1[((b * 16 + o) << 11) + m] = a;
    }
    float* vp = P_V1 + ((size_t)(b * N_) + m) * 16;
    for (int o = 0; o < 16; o++) {
      const float* w = P_WV12 + o * 64;
      float a = 0.0f;
#pragma unroll
      for (int c = 0; c < 64; c++) a += w[c] * in[c];
      vp[o] = a;
    }
  }
  if (og == 2) {
    float p0 = pcs[mm * 4 + 0], p1 = pcs[mm * 4 + 1], p2 = pcs[mm * 4 + 2];
    for (int o = 0; o < 16; o++)
      P_U2[((b * 16 + o) << 11) + m] = P_WU22[o * 4] * p0 + P_WU22[o * 4 + 1] * p1 + P_WU22[o * 4 + 2] * p2;
    float* vp = P_V2 + ((size_t)(b * N_) + m) * 16;
    for (int o = 0; o < 16; o++)
      vp[o] = P_WV22[o * 4] * p0 + P_WV22[o * 4 + 1] * p1 + P_WV22[o * 4 + 2] * p2;
  }
}

// --------------------------------------------------------------------------- id 4
__global__ __launch_bounds__(256) void stats12_kernel(char* base,
    const float* __restrict__ fea_b, const float* __restrict__ xyz_b)
{
  BASE(base);
  PROG(4);
  int b = blockIdx.x >> 5; int n0 = (blockIdx.x & 31) * 64;
  int t = threadIdx.x; int o = t & 15; int kk = t >> 4;
  float fb = fea_b[o], xb = xyz_b[o];
  float s1 = 0, q1 = 0, s2 = 0, q2 = 0;
  for (int nn = 0; nn < 64; nn++) {
    int n = n0 + nn;
    int m = P_IDX[((b << 11) + n) * K_ + kk] & NMASK;
    float a1 = fb + P_U1[((b * 16 + o) << 11) + n] + P_V1[(((size_t)(b << 11) + m) << 4) + o];
    s1 += a1; q1 += a1 * a1;
    float a2 = xb + P_U2[((b * 16 + o) << 11) + n] + P_V2[(((size_t)(b << 11) + m) << 4) + o];
    s2 += a2; q2 += a2 * a2;
  }
  __shared__ float red[256];
  red[t] = s1; __syncthreads();
  if (t < 16) { float s = 0; for (int k2 = 0; k2 < 16; k2++) s += red[k2 * 16 + t]; atomicAdd(&P_ST[ST_S1S + t], s); }
  __syncthreads();
  red[t] = q1; __syncthreads();
  if (t < 16) { float s = 0; for (int k2 = 0; k2 < 16; k2++) s += red[k2 * 16 + t]; atomicAdd(&P_ST[ST_S1Q + t], s); }
  __syncthreads();
  red[t] = s2; __syncthreads();
  if (t < 16) { float s = 0; for (int k2 = 0; k2 < 16; k2++) s += red[k2 * 16 + t]; atomicAdd(&P_ST[ST_S2S + t], s); }
  __syncthreads();
  red[t] = q2; __syncthreads();
  if (t < 16) { float s = 0; for (int k2 = 0; k2 < 16; k2++) s += red[k2 * 16 + t]; atomicAdd(&P_ST[ST_S2Q + t], s); }
}

// --------------------------------------------------------------------------- finalize (ids vary)
__global__ __launch_bounds__(256) void finalize_bn_kernel(char* base,
                                   const float* __restrict__ g,
                                   const float* __restrict__ be,
                                   int sum_off, int sq_off, int sc_off, int sh_off,
                                   int nch, float inv_cnt, int kid)
{
  BASE(base);
  PROG(kid);
  int i = threadIdx.x;
  if (i < nch) {
    float mu = P_ST[sum_off + i] * inv_cnt;
    float var = fmaxf(P_ST[sq_off + i] * inv_cnt - mu * mu, 0.0f);
    float s = g[i] * rsqrtf(var + EPSv);
    P_ST[sc_off + i] = s; P_ST[sh_off + i] = be[i] - mu * s;
  }
}

// --------------------------------------------------------------------------- id 7
__global__ __launch_bounds__(256) void w1_kernel(char* base,
    const float* __restrict__ fea_b, const float* __restrict__ xyz_b)
{
  BASE(base);
  PROG(7);
  int gid = blockIdx.x * 256 + threadIdx.x;    // 262144
  int n = gid & 2047; int c = (gid >> 11) & 15; int b = gid >> 15;
  const int* ip = P_IDX + ((size_t)((b << 11) + n)) * 16;
  float u1 = P_U1[((b * 16 + c) << 11) + n];
  float u2 = P_U2[((b * 16 + c) << 11) + n];
  float c1 = fea_b[c] + u1, c2v = xyz_b[c] + u2;
  float s1 = P_ST[ST_B1SC + c], h1 = P_ST[ST_B1SH + c];
  float s2 = P_ST[ST_B2SC + c], h2 = P_ST[ST_B2SH + c];
  float o16[16];
#pragma unroll
  for (int kk = 0; kk < 16; kk++) {
    int m = ip[kk] & NMASK;
    float a1 = c1 + P_V1[(((size_t)(b << 11) + m) << 4) + c];
    a1 = lrelu(a1 * s1 + h1);
    float a2 = c2v + P_V2[(((size_t)(b << 11) + m) << 4) + c];
    a2 = lrelu(a2 * s2 + h2);
    o16[kk] = a1 * a2;
  }
  float* wp = P_W1 + ((size_t)(b * 16 + c)) * NK_ + ((size_t)n << 4);
#pragma unroll
  for (int j = 0; j < 4; j++)
    *(float4*)(wp + j * 4) = make_float4(o16[4 * j], o16[4 * j + 1], o16[4 * j + 2], o16[4 * j + 3]);
}

// --------------------------------------------------------------------------- id 8
__global__ __launch_bounds__(256) void stats3_kernel(char* base)
{
  BASE(base);
  PROG(8);
  int tid = blockIdx.x * 256 + threadIdx.x;   // grid 512 -> 131072 threads
  float acc[152];
#pragma unroll
  for (int i = 0; i < 152; i++) acc[i] = 0.0f;
  for (int s = 0; s < 2; s++) {
    int g = tid + s * 131072;
    int b = g >> 15; int col = g & 32767;
    float xv[16];
    for (int c = 0; c < 16; c++) xv[c] = P_W1[((size_t)(b * 16 + c)) * NK_ + col];
    int p = 0;
#pragma unroll
    for (int c1 = 0; c1 < 16; c1++) {
      acc[136 + c1] += xv[c1];
#pragma unroll
      for (int c2 = c1; c2 < 16; c2++) acc[p++] += xv[c1] * xv[c2];
    }
  }
  for (int i = 0; i < 152; i++) {
    float vv = acc[i];
#pragma unroll
    for (int off = 32; off > 0; off >>= 1) vv += __shfl_xor(vv, off);
    if ((threadIdx.x & 63) == 0)
      atomicAdd(i < 136 ? &P_ST[ST_S3M + i] : &P_ST[ST_S3V + i - 136], vv);
  }
}

// --------------------------------------------------------------------------- id 9
__global__ __launch_bounds__(256) void finalize_bn3_kernel(char* base,
                                    const float* __restrict__ b1,
                                    const float* __restrict__ g,
                                    const float* __restrict__ be)
{
  BASE(base);
  PROG(9);
  int o = threadIdx.x;
  if (o >= 64) return;
  float A[16];
  for (int c = 0; c < 16; c++) A[c] = P_A12[o * 16 + c];
  float dv = 0.0f;
  for (int c = 0; c < 16; c++) dv += A[c] * P_ST[ST_S3V + c];
  float quad = 0.0f; int p = 0;
  for (int c1 = 0; c1 < 16; c1++)
    for (int c2 = c1; c2 < 16; c2++) {
      float m = P_ST[ST_S3M + p]; p++;
      quad += (c1 == c2 ? 1.0f : 2.0f) * A[c1] * A[c2] * m;
    }
  float bo = b1[o];
  const float inv = 1.0f / 262144.0f;
  float mean = dv * inv + bo;
  float e2 = quad * inv + 2.0f * bo * dv * inv + bo * bo;
  float var = fmaxf(e2 - mean * mean, 0.0f);
  float s = g[o] * rsqrtf(var + EPSv);
  P_ST[ST_B3SC + o] = s; P_ST[ST_B3SH + o] = be[o] - mean * s;
}

// --------------------------------------------------------------------------- id 10
// a4 -> A4[b][n][cc*16+kk]
__global__ __launch_bounds__(256) void a4_kernel(char* base,
                                                 const float* __restrict__ all1_b,
                                                 const float* __restrict__ all2_b)
{
  BASE(base);
  PROG(10);
  int b = blockIdx.x >> 7; int col0 = (blockIdx.x & 127) * 256;
  int t = threadIdx.x;
  __shared__ float sw[16 * 256];
  for (int i = t; i < 16 * 256; i += 256) {
    int c = i >> 8, cc = i & 255;
    sw[i] = P_W1[((size_t)(b * 16 + c)) * NK_ + col0 + cc];
  }
  __syncthreads();
  float in[16];
  for (int c = 0; c < 16; c++) in[c] = sw[c * 256 + t];
  float h[64];
  for (int o = 0; o < 64; o++) {
    const float* wr = P_A12 + o * 16;
    float a = all1_b[o];
#pragma unroll
    for (int c = 0; c < 16; c++) a += wr[c] * in[c];
    h[o] = lrelu(a * P_ST[ST_B3SC + o] + P_ST[ST_B3SH + o]);
  }
  int col = col0 + t; int n = col >> 4; int kk = col & 15;
  float* dst = P_A4 + ((size_t)(b * N_) + n) * 2048 + kk;
  for (int o = 0; o < 128; o++) {
    const float* wr = P_A22 + o * 64;
    float a = all2_b[o];
#pragma unroll
    for (int c = 0; c < 64; c++) a += wr[c] * h[c];
    dst[o * 16] = a;
  }
}

// --------------------------------------------------------------------------- id 11
__global__ __launch_bounds__(256) void stats4_kernel(char* base)
{
  BASE(base);
  PROG(11);
  int cc = blockIdx.x & 127; int ch = blockIdx.x >> 7;   // 32 chunks
  int r0 = ch * 512;
  float s = 0, q = 0;
  for (int rr = threadIdx.x; rr < 512; rr += 256) {
    const float* p = P_A4 + (size_t)(r0 + rr) * 2048 + cc * 16;
#pragma unroll
    for (int j = 0; j < 4; j++) {
      float4 v = *(const float4*)(p + j * 4);
      s += v.x + v.y + v.z + v.w;
      q += v.x * v.x + v.y * v.y + v.z * v.z + v.w * v.w;
    }
  }
  __shared__ float rs[256], rq[256];
  int t = threadIdx.x;
  rs[t] = s; rq[t] = q; __syncthreads();
  for (int st = 128; st > 0; st >>= 1) {
    if (t < st) { rs[t] += rs[t + st]; rq[t] += rq[t + st]; }
    __syncthreads();
  }
  if (t == 0) { atomicAdd(&P_ST[ST_S4S + cc], rs[0]); atomicAdd(&P_ST[ST_S4Q + cc], rq[0]); }
}

// --------------------------------------------------------------------------- id 13
__global__ __launch_bounds__(256) void softmax_kernel(char* base)
{
  BASE(base);
  PROG(13);
  int rid = blockIdx.x * 256 + threadIdx.x;   // 2,097,152
  int cc = rid & 127; int r = rid >> 7;       // r = b*2048 + n
  float s = P_ST[ST_B4SC + cc], h = P_ST[ST_B4SH + cc];
  float* p = P_A4 + (size_t)r * 2048 + cc * 16;
  float v[16];
#pragma unroll
  for (int j = 0; j < 4; j++) {
    float4 u = *(const float4*)(p + j * 4);
    v[4 * j] = u.x; v[4 * j + 1] = u.y; v[4 * j + 2] = u.z; v[4 * j + 3] = u.w;
  }
  float mx = -BIGF;
#pragma unroll
  for (int i = 0; i < 16; i++) {
    float y = lrelu(v[i] * s + h);
    v[i] = y; mx = fmaxf(mx, y);
  }
  float sum = 0.0f;
#pragma unroll
  for (int i = 0; i < 16; i++) { float e = expf(v[i] - mx); v[i] = e; sum += e; }
  float inv = (sum > 0.0f) ? 1.0f / sum : 0.0f;
#pragma unroll
  for (int j = 0; j < 4; j++)
    *(float4*)(p + j * 4) = make_float4(v[4 * j] * inv, v[4 * j + 1] * inv,
                                        v[4 * j + 2] * inv, v[4 * j + 3] * inv);
}

// --------------------------------------------------------------------------- id 14
__global__ __launch_bounds__(256) void qgemm_kernel(char* base)
{
  BASE(base);
  PROG(14);
  int b = blockIdx.x >> 8; int r = blockIdx.x & 255;
  int osp = r & 7; int m0 = (r >> 3) * 64;
  int t = threadIdx.x;
  __shared__ __align__(16) float xsm[64 * 68];
  for (int i = t; i < 4096; i += 256) {
    int c = i & 63, mm = i >> 6;
    xsm[mm * 68 + c] = P_XT[((size_t)(b * N_) + m0 + mm) * 64 + c];
  }
  __syncthreads();
  int mm = t & 63;
  int og = t >> 6;
  float in[64];
  for (int cq = 0; cq < 16; cq++) {
    float4 v = *(const float4*)&xsm[mm * 68 + cq * 4];
    in[cq * 4 + 0] = v.x; in[cq * 4 + 1] = v.y; in[cq * 4 + 2] = v.z; in[cq * 4 + 3] = v.w;
  }
  int m = m0 + mm;
  int obase = osp * 32 + og * 8;
  for (int t9 = 0; t9 < TAP_; t9++) {
    float* qp = P_QB + ((size_t)(b * N_ + m) * TAP_ + t9) * C4_ + obase;
    const float* wq = P_WQ2 + ((size_t)(t9 * 256 + obase)) * 64;
    for (int oi = 0; oi < 8; oi++) {
      const float* w = wq + oi * 64;
      float a = 0.0f;
#pragma unroll
      for (int c = 0; c < 64; c++) a += w[c] * in[c];
      qp[oi] = a;
    }
  }
}

// --------------------------------------------------------------------------- id 15
__global__ __launch_bounds__(256) void inte_fused_kernel(char* base,
                                                         const float* __restrict__ inte_b)
{
  BASE(base);
  PROG(15);
  int b = blockIdx.x >> 9; int n0 = (blockIdx.x & 511) * 4;
  int t = threadIdx.x; int o = t;
  __shared__ int sidx[4][16];
  if (t < 64) sidx[t >> 4][t & 15] = P_IDX[((size_t)(b * N_) + n0 + (t >> 4)) * K_ + (t & 15)] & NMASK;
  __syncthreads();
  float bias = inte_b[o];
  float ssum = 0.0f, ssq = 0.0f;
  for (int nn = 0; nn < 4; nn++) {
    int n = n0 + nn;
    float bse = bias + P_P[((size_t)(b * N_) + n) * C4_ + o];
    float acc[8];
#pragma unroll
    for (int j = 0; j < 8; j++) acc[j] = bse;
    for (int p = 0; p < 16; p++) {
      const float* qr = P_QB + (size_t)(b * N_ + sidx[nn][p]) * TAP_ * C4_ + o;
#pragma unroll
      for (int tt = 0; tt < TAP_; tt++) {
        int j = p - tt;
        if (j >= 0 && j < 8) acc[j] += qr[tt * C4_];
      }
    }
    float* ip = P_IT + ((size_t)(b * N_) + n) * 2048 + o * 8;
#pragma unroll
    for (int j = 0; j < 8; j++) { float v = acc[j]; ip[j] = v; ssum += v; ssq += v * v; }
  }
  atomicAdd(&P_ST[ST_S5S + o], ssum);
  atomicAdd(&P_ST[ST_S5Q + o], ssq);
}

// --------------------------------------------------------------------------- id 17
// final conv v3: 512 threads, k-split x4, all 128 o per block (8 wave-uniform
// o-sections of 16), partials to P_PART.
__global__ __launch_bounds__(512) void final_conv_kernel(char* base)
{
  BASE(base);
  PROG(17);
  int ks = blockIdx.x & 3; int tile = (blockIdx.x >> 2) & 31; int b = blockIdx.x >> 7;
  int n0 = tile * 64;
  int t = threadIdx.x;
  int col = t & 63;
  int osec = t >> 6;           // 0..7, wave-uniform
  int obase = osec * 16;
  __shared__ float tileS[128 * 65];
  __shared__ int sidxT[16 * 64];        // [p][cl]
  __shared__ float sc5s[256], sh5s[256];
  for (int i = t; i < 1024; i += 512) {
    int cl = i & 63, p = i >> 6;
    sidxT[p * 64 + cl] = P_IDX[((size_t)(b * N_) + n0 + cl) * K_ + p] & NMASK;
  }
  if (t < 256) { sc5s[t] = P_ST[ST_B5SC + t]; sh5s[t] = P_ST[ST_B5SH + t]; }
  float acc[16];
#pragma unroll
  for (int oi = 0; oi < 16; oi++) acc[oi] = 0.0f;
  int kbeg = ks * 768;
  for (int k0 = kbeg; k0 < kbeg + 768; k0 += 128) {
    __syncthreads();
    if (k0 < 1024) {
      int c0 = k0 >> 4;
      int cl = t & 63; int pg = t >> 6;        // 0..7
      for (int pi = 0; pi < 2; pi++) {
        int p = pg + pi * 8;
        int m = sidxT[p * 64 + cl];
        const float* xp = P_XT + ((size_t)(b * N_) + m) * 64 + c0;
        float4 v0 = *(const float4*)xp;
        float4 v1 = *(const float4*)(xp + 4);
        tileS[(0 * 16 + p) * 65 + cl] = v0.x;
        tileS[(1 * 16 + p) * 65 + cl] = v0.y;
        tileS[(2 * 16 + p) * 65 + cl] = v0.z;
        tileS[(3 * 16 + p) * 65 + cl] = v0.w;
        tileS[(4 * 16 + p) * 65 + cl] = v1.x;
        tileS[(5 * 16 + p) * 65 + cl] = v1.y;
        tileS[(6 * 16 + p) * 65 + cl] = v1.z;
        tileS[(7 * 16 + p) * 65 + cl] = v1.w;
      }
    } else {
      int kr0 = k0 - 1024;
      int cl = t >> 3; int krg = t & 7;
      size_t rb = ((size_t)(b * N_) + n0 + cl) * 2048 + kr0 + krg * 16;
      for (int j4 = 0; j4 < 4; j4++) {
        float4 iv = *(const float4*)(P_IT + rb + j4 * 4);
        float4 av = *(const float4*)(P_A4 + rb + j4 * 4);
        float vals[4] = {iv.x, iv.y, iv.z, iv.w};
        float aas[4]  = {av.x, av.y, av.z, av.w};
        int krl = krg * 16 + j4 * 4;           // local kc base
        int krgl = kr0 + krl;                  // global kr base
#pragma unroll
        for (int j = 0; j < 4; j++) {
          int o5 = (krgl + j) >> 3;
          float v = lrelu(vals[j] * sc5s[o5] + sh5s[o5]);
          tileS[(krl + j) * 65 + cl] = v * aas[j];
        }
      }
    }
    __syncthreads();
    for (int kc0 = 0; kc0 < 128; kc0 += 2) {
      const float* wr = P_WC2 + (size_t)(k0 + kc0) * C2_ + obase;   // wave-uniform
      float w0[16], w1[16];
#pragma unroll
      for (int oi = 0; oi < 16; oi++) { w0[oi] = wr[oi]; w1[oi] = wr[128 + oi]; }
      float v0 = tileS[kc0 * 65 + col];
      float v1 = tileS[(kc0 + 1) * 65 + col];
#pragma unroll
      for (int oi = 0; oi < 16; oi++) acc[oi] += w0[oi] * v0 + w1[oi] * v1;
    }
  }
  float* op = P_PART + ((size_t)ks * B_ * N_ + (size_t)b * N_ + n0 + col) * C2_ + obase;
#pragma unroll
  for (int oi = 0; oi < 16; oi++) op[oi] = acc[oi];
}

// --------------------------------------------------------------------------- id 18
// reduce partials + S + bias -> OUT2; bn6 stats fused
__global__ __launch_bounds__(256) void reduce_stats_kernel(char* base,
                                                           const float* __restrict__ c2_b)
{
  BASE(base);
  PROG(18);
  int r0 = blockIdx.x * 128;    // grid 128
  int t = threadIdx.x; int o = t & 127; int h = t >> 7;
  const size_t STRIDE = (size_t)B_ * N_ * C2_;
  float cb = c2_b[o];
  float s = 0, q = 0;
  for (int r = r0 + h; r < r0 + 128; r += 2) {
    size_t off = (size_t)r * C2_ + o;
    float v = cb + P_Sb[off] + P_PART[off] + P_PART[STRIDE + off]
            + P_PART[2 * STRIDE + off] + P_PART[3 * STRIDE + off];
    P_OUT2[off] = v;
    s += v; q += v * v;
  }
  __shared__ float rs[256], rq[256];
  rs[t] = s; rq[t] = q; __syncthreads();
  if (t < 128) {
    atomicAdd(&P_ST[ST_S6S + o], rs[t] + rs[t + 128]);
    atomicAdd(&P_ST[ST_S6Q + o], rq[t] + rq[t + 128]);
  }
}

// --------------------------------------------------------------------------- id 20
__global__ __launch_bounds__(256) void output_kernel(char* base, float* __restrict__ out)
{
  BASE(base);
  PROG(20);
  int i = blockIdx.x * 256 + threadIdx.x;
  int j = i & 4095; int f = (i >> 12) & 63; int b = i >> 18;
  int o = 2 * f + (j >> 11); int n = j & 2047;
  float v = P_OUT2[((size_t)(b * N_) + n) * C2_ + o];
  v = v * P_ST[ST_B6SC + o] + P_ST[ST_B6SH + o];
  out[i] = fmaxf(v, 0.0f);
}

// --------------------------------------------------------------------------- diagnostics
__global__ void diag_kernel(char* base, float* __restrict__ out)
{
  BASE(base);
  const int expctd[21] = {1, 6349, 4096, 256, 256, 1, 1, 1024, 512, 1, 1024,
                          4096, 1, 8192, 2048, 4096, 1, 1024, 128, 1, 8192};
  int t = threadIdx.x;
  int bad = 99;
  if (t < 21 && P_PROG[t] != expctd[t]) bad = t;
#pragma unroll
  for (int off = 32; off > 0; off >>= 1) {
    int ob = __shfl_xor(bad, off);
    if (ob < bad) bad = ob;
  }
  if (t == 0 && bad != 99) out[0] = 100.0f + 10.0f * (float)bad;
}

__global__ void code_kernel(float* __restrict__ out, float code)
{
  if (threadIdx.x == 0 && blockIdx.x == 0) out[0] = code;
}

// ---------------------------------------------------------------------------
extern "C" void kernel_launch(void* const* d_in, const int* in_sizes, int n_in,
                              void* d_out, int out_size, void* d_ws, size_t ws_size,
                              hipStream_t stream) {
  const float* x      = (const float*)d_in[0];
  const float* pc     = (const float*)d_in[1];
  const float* fea_w  = (const float*)d_in[2];
  const float* fea_b  = (const float*)d_in[3];
  const float* fea_g  = (const float*)d_in[4];
  const float* fea_be = (const float*)d_in[5];
  const float* xyz_w  = (const float*)d_in[6];
  const float* xyz_b  = (const float*)d_in[7];
  const float* xyz_g  = (const float*)d_in[8];
  const float* xyz_be = (const float*)d_in[9];
  const float* all1_w = (const float*)d_in[10];
  const float* all1_b = (const float*)d_in[11];
  const float* all1_g = (const float*)d_in[12];
  const float* all1_be= (const float*)d_in[13];
  const float* all2_w = (const float*)d_in[14];
  const float* all2_b = (const float*)d_in[15];
  const float* all2_g = (const float*)d_in[16];
  const float* all2_be= (const float*)d_in[17];
  const float* inte_w = (const float*)d_in[18];
  const float* inte_b = (const float*)d_in[19];
  const float* inte_g = (const float*)d_in[20];
  const float* inte_be= (const float*)d_in[21];
  const float* c2_w   = (const float*)d_in[22];
  const float* c2_b   = (const float*)d_in[23];
  const float* c2_g   = (const float*)d_in[24];
  const float* c2_be  = (const float*)d_in[25];
  float* out = (float*)d_out;
  (void)in_sizes; (void)n_in; (void)out_size; (void)d_ws; (void)ws_size;

  if (g_pool_mem == nullptr) {
    code_kernel<<<1, 64, 0, stream>>>(out, 500.0f);
    return;
  }
  char* base = g_pool_mem;

  zero_kernel<<<1, 256, 0, stream>>>(base);
  prep_kernel<<<6349, 256, 0, stream>>>(base, x, fea_w, xyz_w, inte_w, c2_w, all1_w, all2_w);
  knn_kernel<<<4096, 256, 0, stream>>>(base);
  point_gemm_kernel<<<256, 256, 0, stream>>>(base, pc);
  stats12_kernel<<<256, 256, 0, stream>>>(base, fea_b, xyz_b);
  finalize_bn_kernel<<<1, 256, 0, stream>>>(base, fea_g, fea_be, ST_S1S, ST_S1Q, ST_B1SC, ST_B1SH, 16, 1.0f / 262144.0f, 5);
  finalize_bn_kernel<<<1, 256, 0, stream>>>(base, xyz_g, xyz_be, ST_S2S, ST_S2Q, ST_B2SC, ST_B2SH, 16, 1.0f / 262144.0f, 6);
  w1_kernel<<<1024, 256, 0, stream>>>(base, fea_b, xyz_b);
  stats3_kernel<<<512, 256, 0, stream>>>(base);
  finalize_bn3_kernel<<<1, 256, 0, stream>>>(base, all1_b, all1_g, all1_be);
  a4_kernel<<<1024, 256, 0, stream>>>(base, all1_b, all2_b);
  stats4_kernel<<<4096, 256, 0, stream>>>(base);
  finalize_bn_kernel<<<1, 256, 0, stream>>>(base, all2_g, all2_be, ST_S4S, ST_S4Q, ST_B4SC, ST_B4SH, 128, 1.0f / 262144.0f, 12);
  softmax_kernel<<<8192, 256, 0, stream>>>(base);
  qgemm_kernel<<<2048, 256, 0, stream>>>(base);
  inte_fused_kernel<<<4096, 256, 0, stream>>>(base, inte_b);
  finalize_bn_kernel<<<1, 256, 0, stream>>>(base, inte_g, inte_be, ST_S5S, ST_S5Q, ST_B5SC, ST_B5SH, 256, 1.0f / 131072.0f, 16);
  final_conv_kernel<<<1024, 512, 0, stream>>>(base);
  reduce_stats_kernel<<<128, 256, 0, stream>>>(base, c2_b);
  finalize_bn_kernel<<<1, 256, 0, stream>>>(base, c2_g, c2_be, ST_S6S, ST_S6Q, ST_B6SC, ST_B6SH, 128, 1.0f / 16384.0f, 19);
  output_kernel<<<8192, 256, 0, stream>>>(base, out);
  diag_kernel<<<1, 64, 0, stream>>>(base, out);
}

// Round 11
// 2957.507 us; speedup vs baseline: 1.4954x; 1.4954x over previous
//
#include <hip/hip_runtime.h>
#include <math.h>

#define B_   8
#define N_   2048
#define K_   16
#define C2_  128
#define C4_  256
#define KH_  8
#define TAP_ 9
#define NK_  32768
#define EPSv 1e-5f
#define BIGF 3.0e38f
#define NMASK 2047

constexpr size_t AL(size_t x) { return (x + 255) & ~(size_t)255; }
constexpr size_t OFF_XT   = 0;                                                  // f32 [B][N][64]
constexpr size_t OFF_IDX  = OFF_XT  + AL(4ull * B_ * N_ * 64);                  // int [B][N][16]
constexpr size_t OFF_U1   = OFF_IDX + AL(4ull * B_ * N_ * K_);
constexpr size_t OFF_V1   = OFF_U1  + AL(4ull * B_ * 16 * N_);
constexpr size_t OFF_U2   = OFF_V1  + AL(4ull * B_ * N_ * 16);
constexpr size_t OFF_V2   = OFF_U2  + AL(4ull * B_ * 16 * N_);
constexpr size_t OFF_S    = OFF_V2  + AL(4ull * B_ * N_ * 16);                  // f32 [B][N][128]
constexpr size_t OFF_P    = OFF_S   + AL(4ull * B_ * N_ * C2_);                 // f32 [B][N][256]
constexpr size_t OFF_W1   = OFF_P   + AL(4ull * B_ * N_ * C4_);                 // f32 [B][16][NK]
constexpr size_t OFF_QB   = OFF_W1  + AL(4ull * B_ * 16 * NK_);                 // f32 [B][N][9][256]
constexpr size_t OFF_ITB  = OFF_QB  + AL(4ull * (size_t)B_ * N_ * TAP_ * C4_);  // f32 [B][N][2048] (o*8+j)
constexpr size_t OFF_A4B  = OFF_ITB + AL(4ull * (size_t)B_ * N_ * 2048);        // f32 [B][N][2048] (cc*16+kk)
constexpr size_t OFF_PART = OFF_A4B + AL(4ull * (size_t)B_ * N_ * 2048);        // f32 [2][B][N][128]
constexpr size_t OFF_OUT2 = OFF_PART+ AL(4ull * 2 * (size_t)B_ * N_ * C2_);     // f32 [B][N][128]
constexpr size_t OFF_WQ2  = OFF_OUT2+ AL(4ull * B_ * N_ * C2_);
constexpr size_t OFF_WC2  = OFF_WQ2 + AL(4ull * TAP_ * C4_ * 64);
constexpr size_t OFF_WP2  = OFF_WC2 + AL(4ull * 3072 * C2_);
constexpr size_t OFF_WS2  = OFF_WP2 + AL(4ull * C4_ * 64);
constexpr size_t OFF_WU12 = OFF_WS2 + AL(4ull * C2_ * 64);
constexpr size_t OFF_WV12 = OFF_WU12+ AL(4ull * 16 * 64);
constexpr size_t OFF_WU22 = OFF_WV12+ AL(4ull * 16 * 64);
constexpr size_t OFF_WV22 = OFF_WU22+ AL(4ull * 64);
constexpr size_t OFF_A12  = OFF_WV22+ AL(4ull * 64);
constexpr size_t OFF_A22  = OFF_A12 + AL(4ull * 64 * 16);
constexpr size_t OFF_ST   = OFF_A22 + AL(4ull * C2_ * 64);
constexpr size_t OFF_PROG = OFF_ST  + AL(4ull * 4096);
constexpr size_t POOL_SZ  = OFF_PROG + AL(4ull * 64);

static char* g_pool_mem = nullptr;
struct PoolInit {
  PoolInit() { if (hipMalloc((void**)&g_pool_mem, POOL_SZ) != hipSuccess) g_pool_mem = nullptr; }
};
static PoolInit g_pool_init;

// g_st float offsets
#define ST_S1S 0
#define ST_S1Q 16
#define ST_S2S 32
#define ST_S2Q 48
#define ST_S5S 64
#define ST_S5Q 320
#define ST_S4S 576
#define ST_S4Q 704
#define ST_S6S 832
#define ST_S6Q 960
#define ST_B1SC 1088
#define ST_B1SH 1104
#define ST_B2SC 1120
#define ST_B2SH 1136
#define ST_B3SC 1152
#define ST_B3SH 1216
#define ST_B4SC 1280
#define ST_B4SH 1408
#define ST_B5SC 1536
#define ST_B5SH 1792
#define ST_B6SC 2048
#define ST_B6SH 2176
#define ST_S3M  2304
#define ST_S3V  2440

#define BASE(b)  char* bb = (b)
#define P_XT   ((float*)(bb + OFF_XT))
#define P_IDX  ((int*)(bb + OFF_IDX))
#define P_U1   ((float*)(bb + OFF_U1))
#define P_V1   ((float*)(bb + OFF_V1))
#define P_U2   ((float*)(bb + OFF_U2))
#define P_V2   ((float*)(bb + OFF_V2))
#define P_Sb   ((float*)(bb + OFF_S))
#define P_P    ((float*)(bb + OFF_P))
#define P_W1   ((float*)(bb + OFF_W1))
#define P_QB   ((float*)(bb + OFF_QB))
#define P_IT   ((float*)(bb + OFF_ITB))
#define P_A4   ((float*)(bb + OFF_A4B))
#define P_PART ((float*)(bb + OFF_PART))
#define P_OUT2 ((float*)(bb + OFF_OUT2))
#define P_WQ2  ((float*)(bb + OFF_WQ2))
#define P_WC2  ((float*)(bb + OFF_WC2))
#define P_WP2  ((float*)(bb + OFF_WP2))
#define P_WS2  ((float*)(bb + OFF_WS2))
#define P_WU12 ((float*)(bb + OFF_WU12))
#define P_WV12 ((float*)(bb + OFF_WV12))
#define P_WU22 ((float*)(bb + OFF_WU22))
#define P_WV22 ((float*)(bb + OFF_WV22))
#define P_A12  ((float*)(bb + OFF_A12))
#define P_A22  ((float*)(bb + OFF_A22))
#define P_ST   ((float*)(bb + OFF_ST))
#define P_PROG ((int*)(bb + OFF_PROG))

#define PROG(id) do { if (threadIdx.x == 0) atomicAdd(&P_PROG[(id)], 1); } while (0)

static __device__ __forceinline__ float lrelu(float x) { return x >= 0.0f ? x : 0.01f * x; }

// --------------------------------------------------------------------------- id 0
__global__ __launch_bounds__(256) void zero_kernel(char* base)
{
  BASE(base);
  for (int i = threadIdx.x; i < 4096; i += 256) P_ST[i] = 0.0f;
  for (int i = threadIdx.x; i < 64; i += 256) P_PROG[i] = 0;
  __syncthreads();
  if (threadIdx.x == 0) P_PROG[0] = 1;
}

// --------------------------------------------------------------------------- id 1
__global__ __launch_bounds__(256) void prep_kernel(char* base,
    const float* __restrict__ x, const float* __restrict__ fea_w,
    const float* __restrict__ xyz_w, const float* __restrict__ inte_w,
    const float* __restrict__ c2_w, const float* __restrict__ all1_w,
    const float* __restrict__ all2_w)
{
  BASE(base);
  PROG(1);
  int i = blockIdx.x * 256 + threadIdx.x;
  if (i < 1048576) {                       // xT[b][m][c] = x[b][c][m]
    int c = i & 63; int m = (i >> 6) & 2047; int b = i >> 17;
    P_XT[i] = x[((size_t)(b * 64 + c)) * N_ + m];
    return;
  }
  i -= 1048576;
  if (i < 1024) { int c = i & 63, o = i >> 6;
    P_WU12[i] = fea_w[o * 128 + c] - fea_w[o * 128 + 64 + c]; return; }
  i -= 1024;
  if (i < 1024) { int c = i & 63, o = i >> 6;
    P_WV12[i] = fea_w[o * 128 + 64 + c]; return; }
  i -= 1024;
  if (i < 64) { int c = i & 3, o = i >> 2;
    P_WU22[i] = (c < 3) ? (xyz_w[o * 6 + c] - xyz_w[o * 6 + 3 + c]) : 0.0f; return; }
  i -= 64;
  if (i < 64) { int c = i & 3, o = i >> 2;
    P_WV22[i] = (c < 3) ? xyz_w[o * 6 + 3 + c] : 0.0f; return; }
  i -= 64;
  if (i < 16384) { int c = i & 63, o = i >> 6;
    float s = 0.0f;
    for (int t = 0; t < TAP_; t++)
      s += inte_w[(o * 128 + c) * TAP_ + t] - inte_w[(o * 128 + 64 + c) * TAP_ + t];
    P_WP2[i] = s; return; }
  i -= 16384;
  if (i < 147456) { int c = i & 63; int to = i >> 6; int o = to & 255; int tt = to >> 8;
    P_WQ2[i] = inte_w[(o * 128 + 64 + c) * TAP_ + tt]; return; }
  i -= 147456;
  if (i < 8192) { int c = i & 63, o = i >> 6;
    float s = 0.0f;
    for (int p = 0; p < 16; p++)
      s += c2_w[(o * 128 + c) * 32 + p] - c2_w[(o * 128 + 64 + c) * 32 + p];
    P_WS2[i] = s; return; }
  i -= 8192;
  if (i < 393216) { int o = i & 127; int k = i >> 7; float v;
    if (k < 1024) { int c = k >> 4, p = k & 15; v = c2_w[(o * 128 + 64 + c) * 32 + p]; }
    else { int kr = k - 1024; int cc = kr >> 4, kk = kr & 15; v = c2_w[(o * 128 + cc) * 32 + 16 + kk]; }
    P_WC2[i] = v; return; }
  i -= 393216;
  if (i < 1024) { int c = i & 15, o = i >> 4; P_A12[i] = all1_w[o * 16 + c]; return; }
  i -= 1024;
  if (i < 8192) { int c = i & 63, o = i >> 6; P_A22[i] = all2_w[o * 64 + c]; return; }
}

// --------------------------------------------------------------------------- id 2
__global__ __launch_bounds__(256) void knn_kernel(char* base)
{
  BASE(base);
  PROG(2);
  int b = blockIdx.x >> 9; int n0 = (blockIdx.x & 511) * 4;
  int t = threadIdx.x;
  __shared__ float sdist[4][N_];
  __shared__ __align__(16) float xn[4][64];
  __shared__ float sxn[4];
  {
    int nn = t >> 6, c = t & 63;
    xn[nn][c] = P_XT[((size_t)(b * N_) + n0 + nn) * 64 + c];
  }
  __syncthreads();
  if (t < 4) {
    float s = 0.0f;
    for (int c = 0; c < 64; c++) { float v = xn[t][c]; s += v * v; }
    sxn[t] = s;
  }
  __syncthreads();
  float dd[32]; float xs[8];
#pragma unroll
  for (int i = 0; i < 32; i++) dd[i] = 0.0f;
#pragma unroll
  for (int i = 0; i < 8; i++) xs[i] = 0.0f;
  for (int cq = 0; cq < 16; cq++) {
    float4 a0 = *(const float4*)&xn[0][cq * 4];
    float4 a1 = *(const float4*)&xn[1][cq * 4];
    float4 a2 = *(const float4*)&xn[2][cq * 4];
    float4 a3 = *(const float4*)&xn[3][cq * 4];
#pragma unroll
    for (int mi = 0; mi < 8; mi++) {
      const float4 xv = *(const float4*)&P_XT[((size_t)(b * N_) + t + mi * 256) * 64 + cq * 4];
      xs[mi] += xv.x * xv.x + xv.y * xv.y + xv.z * xv.z + xv.w * xv.w;
      dd[0 * 8 + mi] += a0.x * xv.x + a0.y * xv.y + a0.z * xv.z + a0.w * xv.w;
      dd[1 * 8 + mi] += a1.x * xv.x + a1.y * xv.y + a1.z * xv.z + a1.w * xv.w;
      dd[2 * 8 + mi] += a2.x * xv.x + a2.y * xv.y + a2.z * xv.z + a2.w * xv.w;
      dd[3 * 8 + mi] += a3.x * xv.x + a3.y * xv.y + a3.z * xv.z + a3.w * xv.w;
    }
  }
  float sx0 = sxn[0], sx1 = sxn[1], sx2 = sxn[2], sx3 = sxn[3];
#pragma unroll
  for (int mi = 0; mi < 8; mi++) {
    int m = t + mi * 256;
    float d0 = -2.0f * dd[0 * 8 + mi] + sx0 + xs[mi];
    float d1 = -2.0f * dd[1 * 8 + mi] + sx1 + xs[mi];
    float d2 = -2.0f * dd[2 * 8 + mi] + sx2 + xs[mi];
    float d3 = -2.0f * dd[3 * 8 + mi] + sx3 + xs[mi];
    sdist[0][m] = (m == n0 + 0) ? BIGF : d0;
    sdist[1][m] = (m == n0 + 1) ? BIGF : d1;
    sdist[2][m] = (m == n0 + 2) ? BIGF : d2;
    sdist[3][m] = (m == n0 + 3) ? BIGF : d3;
  }
  __syncthreads();
  int ln = t & 63; int wv = t >> 6;
  for (int it = 0; it < K_; it++) {
    float bv = sdist[wv][ln]; int bi = ln;
    for (int mi = 1; mi < 32; mi++) {
      int m = ln + mi * 64;
      float v = sdist[wv][m];
      if (v < bv) { bv = v; bi = m; }
    }
#pragma unroll
    for (int off = 32; off > 0; off >>= 1) {
      float ov = __shfl_xor(bv, off);
      int oi = __shfl_xor(bi, off);
      if (ov < bv || (ov == bv && oi < bi)) { bv = ov; bi = oi; }
    }
    bi &= NMASK;
    if (ln == 0) {
      P_IDX[((size_t)(b * N_) + n0 + wv) * K_ + it] = bi;
      sdist[wv][bi] = BIGF;
    }
    __syncthreads();
  }
}

// --------------------------------------------------------------------------- id 3
__global__ __launch_bounds__(256) void point_gemm_kernel(char* base,
                                                         const float* __restrict__ pc)
{
  BASE(base);
  PROG(3);
  int b = blockIdx.x >> 5; int m0 = (blockIdx.x & 31) * 64;
  int t = threadIdx.x;
  __shared__ __align__(16) float xsm[64 * 68];
  __shared__ float pcs[64 * 4];
  for (int i = t; i < 4096; i += 256) {
    int c = i & 63, mm = i >> 6;
    xsm[mm * 68 + c] = P_XT[((size_t)(b * N_) + m0 + mm) * 64 + c];
  }
  if (t < 192) {
    int mm = t / 3, c = t - mm * 3;
    pcs[mm * 4 + c] = pc[(b * 3 + c) * N_ + m0 + mm];
  }
  __syncthreads();
  int mm = t & 63;
  int og = t >> 6;
  float in[64];
  for (int cq = 0; cq < 16; cq++) {
    float4 v = *(const float4*)&xsm[mm * 68 + cq * 4];
    in[cq * 4 + 0] = v.x; in[cq * 4 + 1] = v.y; in[cq * 4 + 2] = v.z; in[cq * 4 + 3] = v.w;
  }
  int m = m0 + mm;
  {
    float* pp = P_P + ((size_t)(b * N_) + m) * C4_;
    for (int oi = 0; oi < 64; oi++) {
      const float* w = P_WP2 + ((size_t)(og * 64 + oi)) * 64;
      float a = 0.0f;
#pragma unroll
      for (int c = 0; c < 64; c++) a += w[c] * in[c];
      pp[og * 64 + oi] = a;
    }
  }
  if (og < 2) {
    float* sp = P_Sb + ((size_t)(b * N_) + m) * C2_;
    for (int oi = 0; oi < 64; oi++) {
      const float* w = P_WS2 + ((size_t)(og * 64 + oi)) * 64;
      float a = 0.0f;
#pragma unroll
      for (int c = 0; c < 64; c++) a += w[c] * in[c];
      sp[og * 64 + oi] = a;
    }
  }
  if (og == 3) {
    for (int o = 0; o < 16; o++) {
      const float* w = P_WU12 + o * 64;
      float a = 0.0f;
#pragma unroll
      for (int c = 0; c < 64; c++) a += w[c] * in[c];
      P_U1[((b * 16 + o) << 11) + m] = a;
    }
    float* vp = P_V1 + ((size_t)(b * N_) + m) * 16;
    for (int o = 0; o < 16; o++) {
      const float* w = P_WV12 + o * 64;
      float a = 0.0f;
#pragma unroll
      for (int c = 0; c < 64; c++) a += w[c] * in[c];
      vp[o] = a;
    }
  }
  if (og == 2) {
    float p0 = pcs[mm * 4 + 0], p1 = pcs[mm * 4 + 1], p2 = pcs[mm * 4 + 2];
    for (int o = 0; o < 16; o++)
      P_U2[((b * 16 + o) << 11) + m] = P_WU22[o * 4] * p0 + P_WU22[o * 4 + 1] * p1 + P_WU22[o * 4 + 2] * p2;
    float* vp = P_V2 + ((size_t)(b * N_) + m) * 16;
    for (int o = 0; o < 16; o++)
      vp[o] = P_WV22[o * 4] * p0 + P_WV22[o * 4 + 1] * p1 + P_WV22[o * 4 + 2] * p2;
  }
}

// --------------------------------------------------------------------------- id 4
__global__ __launch_bounds__(256) void stats12_kernel(char* base,
    const float* __restrict__ fea_b, const float* __restrict__ xyz_b)
{
  BASE(base);
  PROG(4);
  int b = blockIdx.x >> 5; int n0 = (blockIdx.x & 31) * 64;
  int t = threadIdx.x; int o = t & 15; int kk = t >> 4;
  float fb = fea_b[o], xb = xyz_b[o];
  float s1 = 0, q1 = 0, s2 = 0, q2 = 0;
  for (int nn = 0; nn < 64; nn++) {
    int n = n0 + nn;
    int m = P_IDX[((b << 11) + n) * K_ + kk] & NMASK;
    float a1 = fb + P_U1[((b * 16 + o) << 11) + n] + P_V1[(((size_t)(b << 11) + m) << 4) + o];
    s1 += a1; q1 += a1 * a1;
    float a2 = xb + P_U2[((b * 16 + o) << 11) + n] + P_V2[(((size_t)(b << 11) + m) << 4) + o];
    s2 += a2; q2 += a2 * a2;
  }
  __shared__ float red[256];
  red[t] = s1; __syncthreads();
  if (t < 16) { float s = 0; for (int k2 = 0; k2 < 16; k2++) s += red[k2 * 16 + t]; atomicAdd(&P_ST[ST_S1S + t], s); }
  __syncthreads();
  red[t] = q1; __syncthreads();
  if (t < 16) { float s = 0; for (int k2 = 0; k2 < 16; k2++) s += red[k2 * 16 + t]; atomicAdd(&P_ST[ST_S1Q + t], s); }
  __syncthreads();
  red[t] = s2; __syncthreads();
  if (t < 16) { float s = 0; for (int k2 = 0; k2 < 16; k2++) s += red[k2 * 16 + t]; atomicAdd(&P_ST[ST_S2S + t], s); }
  __syncthreads();
  red[t] = q2; __syncthreads();
  if (t < 16) { float s = 0; for (int k2 = 0; k2 < 16; k2++) s += red[k2 * 16 + t]; atomicAdd(&P_ST[ST_S2Q + t], s); }
}

// --------------------------------------------------------------------------- finalize (ids vary)
__global__ __launch_bounds__(256) void finalize_bn_kernel(char* base,
                                   const float* __restrict__ g,
                                   const float* __restrict__ be,
                                   int sum_off, int sq_off, int sc_off, int sh_off,
                                   int nch, float inv_cnt, int kid)
{
  BASE(base);
  PROG(kid);
  int i = threadIdx.x;
  if (i < nch) {
    float mu = P_ST[sum_off + i] * inv_cnt;
    float var = fmaxf(P_ST[sq_off + i] * inv_cnt - mu * mu, 0.0f);
    float s = g[i] * rsqrtf(var + EPSv);
    P_ST[sc_off + i] = s; P_ST[sh_off + i] = be[i] - mu * s;
  }
}

// --------------------------------------------------------------------------- id 7
__global__ __launch_bounds__(256) void w1_kernel(char* base,
    const float* __restrict__ fea_b, const float* __restrict__ xyz_b)
{
  BASE(base);
  PROG(7);
  int gid = blockIdx.x * 256 + threadIdx.x;    // 262144
  int n = gid & 2047; int c = (gid >> 11) & 15; int b = gid >> 15;
  const int* ip = P_IDX + ((size_t)((b << 11) + n)) * 16;
  float u1 = P_U1[((b * 16 + c) << 11) + n];
  float u2 = P_U2[((b * 16 + c) << 11) + n];
  float c1 = fea_b[c] + u1, c2v = xyz_b[c] + u2;
  float s1 = P_ST[ST_B1SC + c], h1 = P_ST[ST_B1SH + c];
  float s2 = P_ST[ST_B2SC + c], h2 = P_ST[ST_B2SH + c];
  float o16[16];
#pragma unroll
  for (int kk = 0; kk < 16; kk++) {
    int m = ip[kk] & NMASK;
    float a1 = c1 + P_V1[(((size_t)(b << 11) + m) << 4) + c];
    a1 = lrelu(a1 * s1 + h1);
    float a2 = c2v + P_V2[(((size_t)(b << 11) + m) << 4) + c];
    a2 = lrelu(a2 * s2 + h2);
    o16[kk] = a1 * a2;
  }
  float* wp = P_W1 + ((size_t)(b * 16 + c)) * NK_ + ((size_t)n << 4);
#pragma unroll
  for (int j = 0; j < 4; j++)
    *(float4*)(wp + j * 4) = make_float4(o16[4 * j], o16[4 * j + 1], o16[4 * j + 2], o16[4 * j + 3]);
}

// --------------------------------------------------------------------------- id 8
// stats3 v2: LDS tile, one accumulator per thread (no spills).
// grid 256: b = blk>>5, col0 = (blk&31)*1024; 8 chunks of 128 cols.
__global__ __launch_bounds__(256) void stats3_kernel(char* base)
{
  BASE(base);
  PROG(8);
  int b = blockIdx.x >> 5; int col0 = (blockIdx.x & 31) * 1024;
  int t = threadIdx.x;
  __shared__ float sw[16 * 129];
  // decode pair for t<136: (c1,c2) upper triangle
  int c1 = 0, rem = t;
  if (t < 136) {
    while (rem >= 16 - c1) { rem -= 16 - c1; c1++; }
  }
  int c2 = c1 + rem;
  float acc = 0.0f;
  for (int ck = 0; ck < 8; ck++) {
    __syncthreads();
    for (int i = t; i < 2048; i += 256) {
      int c = i >> 7, l = i & 127;
      sw[c * 129 + l] = P_W1[((size_t)(b * 16 + c)) * NK_ + col0 + ck * 128 + l];
    }
    __syncthreads();
    if (t < 136) {
      const float* r1 = sw + c1 * 129;
      const float* r2 = sw + c2 * 129;
      for (int l = 0; l < 128; l++) acc += r1[l] * r2[l];
    } else if (t < 152) {
      const float* r = sw + (t - 136) * 129;
      for (int l = 0; l < 128; l++) acc += r[l];
    }
  }
  if (t < 136) atomicAdd(&P_ST[ST_S3M + t], acc);
  else if (t < 152) atomicAdd(&P_ST[ST_S3V + t - 136], acc);
}

// --------------------------------------------------------------------------- id 9
__global__ __launch_bounds__(256) void finalize_bn3_kernel(char* base,
                                    const float* __restrict__ b1,
                                    const float* __restrict__ g,
                                    const float* __restrict__ be)
{
  BASE(base);
  PROG(9);
  int o = threadIdx.x;
  if (o >= 64) return;
  float A[16];
  for (int c = 0; c < 16; c++) A[c] = P_A12[o * 16 + c];
  float dv = 0.0f;
  for (int c = 0; c < 16; c++) dv += A[c] * P_ST[ST_S3V + c];
  float quad = 0.0f; int p = 0;
  for (int c1 = 0; c1 < 16; c1++)
    for (int c2 = c1; c2 < 16; c2++) {
      float m = P_ST[ST_S3M + p]; p++;
      quad += (c1 == c2 ? 1.0f : 2.0f) * A[c1] * A[c2] * m;
    }
  float bo = b1[o];
  const float inv = 1.0f / 262144.0f;
  float mean = dv * inv + bo;
  float e2 = quad * inv + 2.0f * bo * dv * inv + bo * bo;
  float var = fmaxf(e2 - mean * mean, 0.0f);
  float s = g[o] * rsqrtf(var + EPSv);
  P_ST[ST_B3SC + o] = s; P_ST[ST_B3SH + o] = be[o] - mean * s;
}

// --------------------------------------------------------------------------- id 10
// a4 -> A4[b][n][cc*16+kk]
__global__ __launch_bounds__(256) void a4_kernel(char* base,
                                                 const float* __restrict__ all1_b,
                                                 const float* __restrict__ all2_b)
{
  BASE(base);
  PROG(10);
  int b = blockIdx.x >> 7; int col0 = (blockIdx.x & 127) * 256;
  int t = threadIdx.x;
  __shared__ float sw[16 * 256];
  for (int i = t; i < 16 * 256; i += 256) {
    int c = i >> 8, cc = i & 255;
    sw[i] = P_W1[((size_t)(b * 16 + c)) * NK_ + col0 + cc];
  }
  __syncthreads();
  float in[16];
  for (int c = 0; c < 16; c++) in[c] = sw[c * 256 + t];
  float h[64];
  for (int o = 0; o < 64; o++) {
    const float* wr = P_A12 + o * 16;
    float a = all1_b[o];
#pragma unroll
    for (int c = 0; c < 16; c++) a += wr[c] * in[c];
    h[o] = lrelu(a * P_ST[ST_B3SC + o] + P_ST[ST_B3SH + o]);
  }
  int col = col0 + t; int n = col >> 4; int kk = col & 15;
  float* dst = P_A4 + ((size_t)(b * N_) + n) * 2048 + kk;
  for (int o = 0; o < 128; o++) {
    const float* wr = P_A22 + o * 64;
    float a = all2_b[o];
#pragma unroll
    for (int c = 0; c < 64; c++) a += wr[c] * h[c];
    dst[o * 16] = a;
  }
}

// --------------------------------------------------------------------------- id 11
__global__ __launch_bounds__(256) void stats4_kernel(char* base)
{
  BASE(base);
  PROG(11);
  int cc = blockIdx.x & 127; int ch = blockIdx.x >> 7;   // 32 chunks
  int r0 = ch * 512;
  float s = 0, q = 0;
  for (int rr = threadIdx.x; rr < 512; rr += 256) {
    const float* p = P_A4 + (size_t)(r0 + rr) * 2048 + cc * 16;
#pragma unroll
    for (int j = 0; j < 4; j++) {
      float4 v = *(const float4*)(p + j * 4);
      s += v.x + v.y + v.z + v.w;
      q += v.x * v.x + v.y * v.y + v.z * v.z + v.w * v.w;
    }
  }
  __shared__ float rs[256], rq[256];
  int t = threadIdx.x;
  rs[t] = s; rq[t] = q; __syncthreads();
  for (int st = 128; st > 0; st >>= 1) {
    if (t < st) { rs[t] += rs[t + st]; rq[t] += rq[t + st]; }
    __syncthreads();
  }
  if (t == 0) { atomicAdd(&P_ST[ST_S4S + cc], rs[0]); atomicAdd(&P_ST[ST_S4Q + cc], rq[0]); }
}

// --------------------------------------------------------------------------- id 13
__global__ __launch_bounds__(256) void softmax_kernel(char* base)
{
  BASE(base);
  PROG(13);
  int rid = blockIdx.x * 256 + threadIdx.x;   // 2,097,152
  int cc = rid & 127; int r = rid >> 7;       // r = b*2048 + n
  float s = P_ST[ST_B4SC + cc], h = P_ST[ST_B4SH + cc];
  float* p = P_A4 + (size_t)r * 2048 + cc * 16;
  float v[16];
#pragma unroll
  for (int j = 0; j < 4; j++) {
    float4 u = *(const float4*)(p + j * 4);
    v[4 * j] = u.x; v[4 * j + 1] = u.y; v[4 * j + 2] = u.z; v[4 * j + 3] = u.w;
  }
  float mx = -BIGF;
#pragma unroll
  for (int i = 0; i < 16; i++) {
    float y = lrelu(v[i] * s + h);
    v[i] = y; mx = fmaxf(mx, y);
  }
  float sum = 0.0f;
#pragma unroll
  for (int i = 0; i < 16; i++) { float e = expf(v[i] - mx); v[i] = e; sum += e; }
  float inv = (sum > 0.0f) ? 1.0f / sum : 0.0f;
#pragma unroll
  for (int j = 0; j < 4; j++)
    *(float4*)(p + j * 4) = make_float4(v[4 * j] * inv, v[4 * j + 1] * inv,
                                        v[4 * j + 2] * inv, v[4 * j + 3] * inv);
}

// --------------------------------------------------------------------------- id 14
__global__ __launch_bounds__(256) void qgemm_kernel(char* base)
{
  BASE(base);
  PROG(14);
  int b = blockIdx.x >> 8; int r = blockIdx.x & 255;
  int osp = r & 7; int m0 = (r >> 3) * 64;
  int t = threadIdx.x;
  __shared__ __align__(16) float xsm[64 * 68];
  for (int i = t; i < 4096; i += 256) {
    int c = i & 63, mm = i >> 6;
    xsm[mm * 68 + c] = P_XT[((size_t)(b * N_) + m0 + mm) * 64 + c];
  }
  __syncthreads();
  int mm = t & 63;
  int og = t >> 6;
  float in[64];
  for (int cq = 0; cq < 16; cq++) {
    float4 v = *(const float4*)&xsm[mm * 68 + cq * 4];
    in[cq * 4 + 0] = v.x; in[cq * 4 + 1] = v.y; in[cq * 4 + 2] = v.z; in[cq * 4 + 3] = v.w;
  }
  int m = m0 + mm;
  int obase = osp * 32 + og * 8;
  for (int t9 = 0; t9 < TAP_; t9++) {
    float* qp = P_QB + ((size_t)(b * N_ + m) * TAP_ + t9) * C4_ + obase;
    const float* wq = P_WQ2 + ((size_t)(t9 * 256 + obase)) * 64;
    for (int oi = 0; oi < 8; oi++) {
      const float* w = wq + oi * 64;
      float a = 0.0f;
#pragma unroll
      for (int c = 0; c < 64; c++) a += w[c] * in[c];
      qp[oi] = a;
    }
  }
}

// --------------------------------------------------------------------------- id 15
__global__ __launch_bounds__(256) void inte_fused_kernel(char* base,
                                                         const float* __restrict__ inte_b)
{
  BASE(base);
  PROG(15);
  int b = blockIdx.x >> 9; int n0 = (blockIdx.x & 511) * 4;
  int t = threadIdx.x; int o = t;
  __shared__ int sidx[4][16];
  if (t < 64) sidx[t >> 4][t & 15] = P_IDX[((size_t)(b * N_) + n0 + (t >> 4)) * K_ + (t & 15)] & NMASK;
  __syncthreads();
  float bias = inte_b[o];
  float ssum = 0.0f, ssq = 0.0f;
  for (int nn = 0; nn < 4; nn++) {
    int n = n0 + nn;
    float bse = bias + P_P[((size_t)(b * N_) + n) * C4_ + o];
    float acc[8];
#pragma unroll
    for (int j = 0; j < 8; j++) acc[j] = bse;
    for (int p = 0; p < 16; p++) {
      const float* qr = P_QB + (size_t)(b * N_ + sidx[nn][p]) * TAP_ * C4_ + o;
#pragma unroll
      for (int tt = 0; tt < TAP_; tt++) {
        int j = p - tt;
        if (j >= 0 && j < 8) acc[j] += qr[tt * C4_];
      }
    }
    float* ip = P_IT + ((size_t)(b * N_) + n) * 2048 + o * 8;
#pragma unroll
    for (int j = 0; j < 8; j++) { float v = acc[j]; ip[j] = v; ssum += v; ssq += v * v; }
  }
  atomicAdd(&P_ST[ST_S5S + o], ssum);
  atomicAdd(&P_ST[ST_S5Q + o], ssq);
}

// --------------------------------------------------------------------------- id 17
// final conv v4: round-9 body (scalarized weights, conflict-free staging)
// + k-split x2.  grid 1024 = ks(2) x g(2) x tile(32) x b(8), 256 threads.
__global__ __launch_bounds__(256) void final_conv_kernel(char* base)
{
  BASE(base);
  PROG(17);
  int ks = blockIdx.x & 1; int g = (blockIdx.x >> 1) & 1;
  int tile = (blockIdx.x >> 2) & 31; int b = blockIdx.x >> 7;
  int n0 = tile * 64;
  int t = threadIdx.x;
  int col = t & 63;
  int osec = t >> 6;
  int obase = g * 64 + osec * 16;
  __shared__ float tileS[128 * 65];
  __shared__ int sidxT[16 * 64];        // [p][cl]
  __shared__ float sc5s[256], sh5s[256];
  for (int i = t; i < 1024; i += 256) {
    int cl = i & 63, p = i >> 6;
    sidxT[p * 64 + cl] = P_IDX[((size_t)(b * N_) + n0 + cl) * K_ + p] & NMASK;
  }
  sc5s[t] = P_ST[ST_B5SC + t];
  sh5s[t] = P_ST[ST_B5SH + t];
  float acc[16];
#pragma unroll
  for (int oi = 0; oi < 16; oi++) acc[oi] = 0.0f;
  int kbeg = ks * 1536;
  for (int k0 = kbeg; k0 < kbeg + 1536; k0 += 128) {
    __syncthreads();
    if (k0 < 1024) {
      int c0 = k0 >> 4;
      int cl = t & 63; int pg = t >> 6;
      for (int pp = 0; pp < 4; pp++) {
        int p = pg * 4 + pp;
        int m = sidxT[p * 64 + cl];
        const float* xp = P_XT + ((size_t)(b * N_) + m) * 64 + c0;
        float4 v0 = *(const float4*)xp;
        float4 v1 = *(const float4*)(xp + 4);
        tileS[(0 * 16 + p) * 65 + cl] = v0.x;
        tileS[(1 * 16 + p) * 65 + cl] = v0.y;
        tileS[(2 * 16 + p) * 65 + cl] = v0.z;
        tileS[(3 * 16 + p) * 65 + cl] = v0.w;
        tileS[(4 * 16 + p) * 65 + cl] = v1.x;
        tileS[(5 * 16 + p) * 65 + cl] = v1.y;
        tileS[(6 * 16 + p) * 65 + cl] = v1.z;
        tileS[(7 * 16 + p) * 65 + cl] = v1.w;
      }
    } else {
      int kr = (k0 - 1024) + (t & 127);
      int hf = t >> 7;
      float s5 = sc5s[kr >> 3], h5 = sh5s[kr >> 3];
      int kc = t & 127;
      for (int q = 0; q < 32; q++) {
        int cl = hf * 32 + q;
        size_t rb = ((size_t)(b * N_) + n0 + cl) * 2048 + kr;
        float v = P_IT[rb];
        v = lrelu(v * s5 + h5);
        tileS[kc * 65 + cl] = v * P_A4[rb];
      }
    }
    __syncthreads();
    for (int kc = 0; kc < 128; kc++) {
      float v = tileS[kc * 65 + col];
      const float* wr = P_WC2 + (size_t)(k0 + kc) * C2_ + obase;
#pragma unroll
      for (int oi = 0; oi < 16; oi++) acc[oi] += wr[oi] * v;
    }
  }
  float* op = P_PART + ((size_t)ks * B_ * N_ + (size_t)b * N_ + n0 + col) * C2_ + obase;
#pragma unroll
  for (int oi = 0; oi < 16; oi++) op[oi] = acc[oi];
}

// --------------------------------------------------------------------------- id 18
// reduce partials + S + bias -> OUT2; bn6 stats fused
__global__ __launch_bounds__(256) void reduce_stats_kernel(char* base,
                                                           const float* __restrict__ c2_b)
{
  BASE(base);
  PROG(18);
  int r0 = blockIdx.x * 128;    // grid 128
  int t = threadIdx.x; int o = t & 127; int h = t >> 7;
  const size_t STRIDE = (size_t)B_ * N_ * C2_;
  float cb = c2_b[o];
  float s = 0, q = 0;
  for (int r = r0 + h; r < r0 + 128; r += 2) {
    size_t off = (size_t)r * C2_ + o;
    float v = cb + P_Sb[off] + P_PART[off] + P_PART[STRIDE + off];
    P_OUT2[off] = v;
    s += v; q += v * v;
  }
  __shared__ float rs[256], rq[256];
  rs[t] = s; rq[t] = q; __syncthreads();
  if (t < 128) {
    atomicAdd(&P_ST[ST_S6S + o], rs[t] + rs[t + 128]);
    atomicAdd(&P_ST[ST_S6Q + o], rq[t] + rq[t + 128]);
  }
}

// --------------------------------------------------------------------------- id 20
__global__ __launch_bounds__(256) void output_kernel(char* base, float* __restrict__ out)
{
  BASE(base);
  PROG(20);
  int i = blockIdx.x * 256 + threadIdx.x;
  int j = i & 4095; int f = (i >> 12) & 63; int b = i >> 18;
  int o = 2 * f + (j >> 11); int n = j & 2047;
  float v = P_OUT2[((size_t)(b * N_) + n) * C2_ + o];
  v = v * P_ST[ST_B6SC + o] + P_ST[ST_B6SH + o];
  out[i] = fmaxf(v, 0.0f);
}

// --------------------------------------------------------------------------- diagnostics
__global__ void diag_kernel(char* base, float* __restrict__ out)
{
  BASE(base);
  const int expctd[21] = {1, 6349, 4096, 256, 256, 1, 1, 1024, 256, 1, 1024,
                          4096, 1, 8192, 2048, 4096, 1, 1024, 128, 1, 8192};
  int t = threadIdx.x;
  int bad = 99;
  if (t < 21 && P_PROG[t] != expctd[t]) bad = t;
#pragma unroll
  for (int off = 32; off > 0; off >>= 1) {
    int ob = __shfl_xor(bad, off);
    if (ob < bad) bad = ob;
  }
  if (t == 0 && bad != 99) out[0] = 100.0f + 10.0f * (float)bad;
}

__global__ void code_kernel(float* __restrict__ out, float code)
{
  if (threadIdx.x == 0 && blockIdx.x == 0) out[0] = code;
}

// ---------------------------------------------------------------------------
extern "C" void kernel_launch(void* const* d_in, const int* in_sizes, int n_in,
                              void* d_out, int out_size, void* d_ws, size_t ws_size,
                              hipStream_t stream) {
  const float* x      = (const float*)d_in[0];
  const float* pc     = (const float*)d_in[1];
  const float* fea_w  = (const float*)d_in[2];
  const float* fea_b  = (const float*)d_in[3];
  const float* fea_g  = (const float*)d_in[4];
  const float* fea_be = (const float*)d_in[5];
  const float* xyz_w  = (const float*)d_in[6];
  const float* xyz_b  = (const float*)d_in[7];
  const float* xyz_g  = (const float*)d_in[8];
  const float* xyz_be = (const float*)d_in[9];
  const float* all1_w = (const float*)d_in[10];
  const float* all1_b = (const float*)d_in[11];
  const float* all1_g = (const float*)d_in[12];
  const float* all1_be= (const float*)d_in[13];
  const float* all2_w = (const float*)d_in[14];
  const float* all2_b = (const float*)d_in[15];
  const float* all2_g = (const float*)d_in[16];
  const float* all2_be= (const float*)d_in[17];
  const float* inte_w = (const float*)d_in[18];
  const float* inte_b = (const float*)d_in[19];
  const float* inte_g = (const float*)d_in[20];
  const float* inte_be= (const float*)d_in[21];
  const float* c2_w   = (const float*)d_in[22];
  const float* c2_b   = (const float*)d_in[23];
  const float* c2_g   = (const float*)d_in[24];
  const float* c2_be  = (const float*)d_in[25];
  float* out = (float*)d_out;
  (void)in_sizes; (void)n_in; (void)out_size; (void)d_ws; (void)ws_size;

  if (g_pool_mem == nullptr) {
    code_kernel<<<1, 64, 0, stream>>>(out, 500.0f);
    return;
  }
  char* base = g_pool_mem;

  zero_kernel<<<1, 256, 0, stream>>>(base);
  prep_kernel<<<6349, 256, 0, stream>>>(base, x, fea_w, xyz_w, inte_w, c2_w, all1_w, all2_w);
  knn_kernel<<<4096, 256, 0, stream>>>(base);
  point_gemm_kernel<<<256, 256, 0, stream>>>(base, pc);
  stats12_kernel<<<256, 256, 0, stream>>>(base, fea_b, xyz_b);
  finalize_bn_kernel<<<1, 256, 0, stream>>>(base, fea_g, fea_be, ST_S1S, ST_S1Q, ST_B1SC, ST_B1SH, 16, 1.0f / 262144.0f, 5);
  finalize_bn_kernel<<<1, 256, 0, stream>>>(base, xyz_g, xyz_be, ST_S2S, ST_S2Q, ST_B2SC, ST_B2SH, 16, 1.0f / 262144.0f, 6);
  w1_kernel<<<1024, 256, 0, stream>>>(base, fea_b, xyz_b);
  stats3_kernel<<<256, 256, 0, stream>>>(base);
  finalize_bn3_kernel<<<1, 256, 0, stream>>>(base, all1_b, all1_g, all1_be);
  a4_kernel<<<1024, 256, 0, stream>>>(base, all1_b, all2_b);
  stats4_kernel<<<4096, 256, 0, stream>>>(base);
  finalize_bn_kernel<<<1, 256, 0, stream>>>(base, all2_g, all2_be, ST_S4S, ST_S4Q, ST_B4SC, ST_B4SH, 128, 1.0f / 262144.0f, 12);
  softmax_kernel<<<8192, 256, 0, stream>>>(base);
  qgemm_kernel<<<2048, 256, 0, stream>>>(base);
  inte_fused_kernel<<<4096, 256, 0, stream>>>(base, inte_b);
  finalize_bn_kernel<<<1, 256, 0, stream>>>(base, inte_g, inte_be, ST_S5S, ST_S5Q, ST_B5SC, ST_B5SH, 256, 1.0f / 131072.0f, 16);
  final_conv_kernel<<<1024, 256, 0, stream>>>(base);
  reduce_stats_kernel<<<128, 256, 0, stream>>>(base, c2_b);
  finalize_bn_kernel<<<1, 256, 0, stream>>>(base, c2_g, c2_be, ST_S6S, ST_S6Q, ST_B6SC, ST_B6SH, 128, 1.0f / 16384.0f, 19);
  output_kernel<<<8192, 256, 0, stream>>>(base, out);
  diag_kernel<<<1, 64, 0, stream>>>(base, out);
}

// Round 12
// 2910.884 us; speedup vs baseline: 1.5193x; 1.0160x over previous
//
#include <hip/hip_runtime.h>
#include <math.h>

typedef unsigned short ushort_t;

#define B_   8
#define N_   2048
#define K_   16
#define C2_  128
#define C4_  256
#define KH_  8
#define TAP_ 9
#define NK_  32768
#define EPSv 1e-5f
#define BIGF 3.0e38f
#define NMASK 2047

constexpr size_t AL(size_t x) { return (x + 255) & ~(size_t)255; }
constexpr size_t OFF_XT   = 0;                                                  // f32 [B][N][64]
constexpr size_t OFF_IDX  = OFF_XT  + AL(4ull * B_ * N_ * 64);
constexpr size_t OFF_U1   = OFF_IDX + AL(4ull * B_ * N_ * K_);
constexpr size_t OFF_V1   = OFF_U1  + AL(4ull * B_ * 16 * N_);
constexpr size_t OFF_U2   = OFF_V1  + AL(4ull * B_ * N_ * 16);
constexpr size_t OFF_V2   = OFF_U2  + AL(4ull * B_ * 16 * N_);
constexpr size_t OFF_S    = OFF_V2  + AL(4ull * B_ * N_ * 16);                  // f32 [B][N][128]
constexpr size_t OFF_P    = OFF_S   + AL(4ull * B_ * N_ * C2_);                 // f32 [B][N][256]
constexpr size_t OFF_W1   = OFF_P   + AL(4ull * B_ * N_ * C4_);                 // f32 [B][16][NK]
constexpr size_t OFF_QB   = OFF_W1  + AL(4ull * B_ * 16 * NK_);                 // bf16 [B][N][9][256]
constexpr size_t OFF_ITB  = OFF_QB  + AL(2ull * (size_t)B_ * N_ * TAP_ * C4_);  // bf16 [B][N][2048]
constexpr size_t OFF_A4B  = OFF_ITB + AL(2ull * (size_t)B_ * N_ * 2048);        // bf16 [B][N][2048]
constexpr size_t OFF_M    = OFF_A4B + AL(2ull * (size_t)B_ * N_ * 2048);        // bf16 [B][N][2048]
constexpr size_t OFF_PART = OFF_M   + AL(2ull * (size_t)B_ * N_ * 2048);        // f32 [2][B][N][128]
constexpr size_t OFF_OUT2 = OFF_PART+ AL(4ull * 2 * (size_t)B_ * N_ * C2_);     // f32 [B][N][128]
constexpr size_t OFF_WQ2  = OFF_OUT2+ AL(4ull * B_ * N_ * C2_);
constexpr size_t OFF_WC2  = OFF_WQ2 + AL(4ull * TAP_ * C4_ * 64);
constexpr size_t OFF_WP2  = OFF_WC2 + AL(4ull * 3072 * C2_);
constexpr size_t OFF_WS2  = OFF_WP2 + AL(4ull * C4_ * 64);
constexpr size_t OFF_WU12 = OFF_WS2 + AL(4ull * C2_ * 64);
constexpr size_t OFF_WV12 = OFF_WU12+ AL(4ull * 16 * 64);
constexpr size_t OFF_WU22 = OFF_WV12+ AL(4ull * 16 * 64);
constexpr size_t OFF_WV22 = OFF_WU22+ AL(4ull * 64);
constexpr size_t OFF_A12  = OFF_WV22+ AL(4ull * 64);
constexpr size_t OFF_A22  = OFF_A12 + AL(4ull * 64 * 16);
constexpr size_t OFF_ST   = OFF_A22 + AL(4ull * C2_ * 64);
constexpr size_t OFF_PROG = OFF_ST  + AL(4ull * 4096);
constexpr size_t POOL_SZ  = OFF_PROG + AL(4ull * 64);

static char* g_pool_mem = nullptr;
struct PoolInit {
  PoolInit() { if (hipMalloc((void**)&g_pool_mem, POOL_SZ) != hipSuccess) g_pool_mem = nullptr; }
};
static PoolInit g_pool_init;

// g_st float offsets
#define ST_S1S 0
#define ST_S1Q 16
#define ST_S2S 32
#define ST_S2Q 48
#define ST_S5S 64
#define ST_S5Q 320
#define ST_S4S 576
#define ST_S4Q 704
#define ST_S6S 832
#define ST_S6Q 960
#define ST_B1SC 1088
#define ST_B1SH 1104
#define ST_B2SC 1120
#define ST_B2SH 1136
#define ST_B3SC 1152
#define ST_B3SH 1216
#define ST_B4SC 1280
#define ST_B4SH 1408
#define ST_B5SC 1536
#define ST_B5SH 1792
#define ST_B6SC 2048
#define ST_B6SH 2176
#define ST_S3M  2304
#define ST_S3V  2440

#define BASE(b)  char* bb = (b)
#define P_XT   ((float*)(bb + OFF_XT))
#define P_IDX  ((int*)(bb + OFF_IDX))
#define P_U1   ((float*)(bb + OFF_U1))
#define P_V1   ((float*)(bb + OFF_V1))
#define P_U2   ((float*)(bb + OFF_U2))
#define P_V2   ((float*)(bb + OFF_V2))
#define P_Sb   ((float*)(bb + OFF_S))
#define P_P    ((float*)(bb + OFF_P))
#define P_W1   ((float*)(bb + OFF_W1))
#define P_QB   ((ushort_t*)(bb + OFF_QB))
#define P_IT   ((ushort_t*)(bb + OFF_ITB))
#define P_A4   ((ushort_t*)(bb + OFF_A4B))
#define P_M    ((ushort_t*)(bb + OFF_M))
#define P_PART ((float*)(bb + OFF_PART))
#define P_OUT2 ((float*)(bb + OFF_OUT2))
#define P_WQ2  ((float*)(bb + OFF_WQ2))
#define P_WC2  ((float*)(bb + OFF_WC2))
#define P_WP2  ((float*)(bb + OFF_WP2))
#define P_WS2  ((float*)(bb + OFF_WS2))
#define P_WU12 ((float*)(bb + OFF_WU12))
#define P_WV12 ((float*)(bb + OFF_WV12))
#define P_WU22 ((float*)(bb + OFF_WU22))
#define P_WV22 ((float*)(bb + OFF_WV22))
#define P_A12  ((float*)(bb + OFF_A12))
#define P_A22  ((float*)(bb + OFF_A22))
#define P_ST   ((float*)(bb + OFF_ST))
#define P_PROG ((int*)(bb + OFF_PROG))

#define PROG(id) do { if (threadIdx.x == 0) atomicAdd(&P_PROG[(id)], 1); } while (0)

static __device__ __forceinline__ float lrelu(float x) { return x >= 0.0f ? x : 0.01f * x; }
static __device__ __forceinline__ float bf2f(unsigned h) {
  union { float f; unsigned u; } v; v.u = h << 16; return v.f;
}
static __device__ __forceinline__ ushort_t f2bf(float f) {
  union { float f; unsigned u; } v; v.f = f;
  unsigned r = v.u + 0x7fffu + ((v.u >> 16) & 1u);
  return (ushort_t)(r >> 16);
}

// --------------------------------------------------------------------------- id 0
__global__ __launch_bounds__(256) void zero_kernel(char* base)
{
  BASE(base);
  for (int i = threadIdx.x; i < 4096; i += 256) P_ST[i] = 0.0f;
  for (int i = threadIdx.x; i < 64; i += 256) P_PROG[i] = 0;
  __syncthreads();
  if (threadIdx.x == 0) P_PROG[0] = 1;
}

// --------------------------------------------------------------------------- id 1
__global__ __launch_bounds__(256) void prep_kernel(char* base,
    const float* __restrict__ x, const float* __restrict__ fea_w,
    const float* __restrict__ xyz_w, const float* __restrict__ inte_w,
    const float* __restrict__ c2_w, const float* __restrict__ all1_w,
    const float* __restrict__ all2_w)
{
  BASE(base);
  PROG(1);
  int i = blockIdx.x * 256 + threadIdx.x;
  if (i < 1048576) {                       // xT[b][m][c] = x[b][c][m]
    int c = i & 63; int m = (i >> 6) & 2047; int b = i >> 17;
    P_XT[i] = x[((size_t)(b * 64 + c)) * N_ + m];
    return;
  }
  i -= 1048576;
  if (i < 1024) { int c = i & 63, o = i >> 6;
    P_WU12[i] = fea_w[o * 128 + c] - fea_w[o * 128 + 64 + c]; return; }
  i -= 1024;
  if (i < 1024) { int c = i & 63, o = i >> 6;
    P_WV12[i] = fea_w[o * 128 + 64 + c]; return; }
  i -= 1024;
  if (i < 64) { int c = i & 3, o = i >> 2;
    P_WU22[i] = (c < 3) ? (xyz_w[o * 6 + c] - xyz_w[o * 6 + 3 + c]) : 0.0f; return; }
  i -= 64;
  if (i < 64) { int c = i & 3, o = i >> 2;
    P_WV22[i] = (c < 3) ? xyz_w[o * 6 + 3 + c] : 0.0f; return; }
  i -= 64;
  if (i < 16384) { int c = i & 63, o = i >> 6;
    float s = 0.0f;
    for (int t = 0; t < TAP_; t++)
      s += inte_w[(o * 128 + c) * TAP_ + t] - inte_w[(o * 128 + 64 + c) * TAP_ + t];
    P_WP2[i] = s; return; }
  i -= 16384;
  if (i < 147456) { int c = i & 63; int to = i >> 6; int o = to & 255; int tt = to >> 8;
    P_WQ2[i] = inte_w[(o * 128 + 64 + c) * TAP_ + tt]; return; }
  i -= 147456;
  if (i < 8192) { int c = i & 63, o = i >> 6;
    float s = 0.0f;
    for (int p = 0; p < 16; p++)
      s += c2_w[(o * 128 + c) * 32 + p] - c2_w[(o * 128 + 64 + c) * 32 + p];
    P_WS2[i] = s; return; }
  i -= 8192;
  if (i < 393216) { int o = i & 127; int k = i >> 7; float v;
    if (k < 1024) { int c = k >> 4, p = k & 15; v = c2_w[(o * 128 + 64 + c) * 32 + p]; }
    else { int kr = k - 1024; int cc = kr >> 4, kk = kr & 15; v = c2_w[(o * 128 + cc) * 32 + 16 + kk]; }
    P_WC2[i] = v; return; }
  i -= 393216;
  if (i < 1024) { int c = i & 15, o = i >> 4; P_A12[i] = all1_w[o * 16 + c]; return; }
  i -= 1024;
  if (i < 8192) { int c = i & 63, o = i >> 6; P_A22[i] = all2_w[o * 64 + c]; return; }
}

// --------------------------------------------------------------------------- id 2
__global__ __launch_bounds__(256) void knn_kernel(char* base)
{
  BASE(base);
  PROG(2);
  int b = blockIdx.x >> 9; int n0 = (blockIdx.x & 511) * 4;
  int t = threadIdx.x;
  __shared__ float sdist[4][N_];
  __shared__ __align__(16) float xn[4][64];
  __shared__ float sxn[4];
  {
    int nn = t >> 6, c = t & 63;
    xn[nn][c] = P_XT[((size_t)(b * N_) + n0 + nn) * 64 + c];
  }
  __syncthreads();
  if (t < 4) {
    float s = 0.0f;
    for (int c = 0; c < 64; c++) { float v = xn[t][c]; s += v * v; }
    sxn[t] = s;
  }
  __syncthreads();
  float dd[32]; float xs[8];
#pragma unroll
  for (int i = 0; i < 32; i++) dd[i] = 0.0f;
#pragma unroll
  for (int i = 0; i < 8; i++) xs[i] = 0.0f;
  for (int cq = 0; cq < 16; cq++) {
    float4 a0 = *(const float4*)&xn[0][cq * 4];
    float4 a1 = *(const float4*)&xn[1][cq * 4];
    float4 a2 = *(const float4*)&xn[2][cq * 4];
    float4 a3 = *(const float4*)&xn[3][cq * 4];
#pragma unroll
    for (int mi = 0; mi < 8; mi++) {
      const float4 xv = *(const float4*)&P_XT[((size_t)(b * N_) + t + mi * 256) * 64 + cq * 4];
      xs[mi] += xv.x * xv.x + xv.y * xv.y + xv.z * xv.z + xv.w * xv.w;
      dd[0 * 8 + mi] += a0.x * xv.x + a0.y * xv.y + a0.z * xv.z + a0.w * xv.w;
      dd[1 * 8 + mi] += a1.x * xv.x + a1.y * xv.y + a1.z * xv.z + a1.w * xv.w;
      dd[2 * 8 + mi] += a2.x * xv.x + a2.y * xv.y + a2.z * xv.z + a2.w * xv.w;
      dd[3 * 8 + mi] += a3.x * xv.x + a3.y * xv.y + a3.z * xv.z + a3.w * xv.w;
    }
  }
  float sx0 = sxn[0], sx1 = sxn[1], sx2 = sxn[2], sx3 = sxn[3];
#pragma unroll
  for (int mi = 0; mi < 8; mi++) {
    int m = t + mi * 256;
    float d0 = -2.0f * dd[0 * 8 + mi] + sx0 + xs[mi];
    float d1 = -2.0f * dd[1 * 8 + mi] + sx1 + xs[mi];
    float d2 = -2.0f * dd[2 * 8 + mi] + sx2 + xs[mi];
    float d3 = -2.0f * dd[3 * 8 + mi] + sx3 + xs[mi];
    sdist[0][m] = (m == n0 + 0) ? BIGF : d0;
    sdist[1][m] = (m == n0 + 1) ? BIGF : d1;
    sdist[2][m] = (m == n0 + 2) ? BIGF : d2;
    sdist[3][m] = (m == n0 + 3) ? BIGF : d3;
  }
  __syncthreads();
  int ln = t & 63; int wv = t >> 6;
  for (int it = 0; it < K_; it++) {
    float bv = sdist[wv][ln]; int bi = ln;
    for (int mi = 1; mi < 32; mi++) {
      int m = ln + mi * 64;
      float v = sdist[wv][m];
      if (v < bv) { bv = v; bi = m; }
    }
#pragma unroll
    for (int off = 32; off > 0; off >>= 1) {
      float ov = __shfl_xor(bv, off);
      int oi = __shfl_xor(bi, off);
      if (ov < bv || (ov == bv && oi < bi)) { bv = ov; bi = oi; }
    }
    bi &= NMASK;
    if (ln == 0) {
      P_IDX[((size_t)(b * N_) + n0 + wv) * K_ + it] = bi;
      sdist[wv][bi] = BIGF;
    }
    __syncthreads();
  }
}

// --------------------------------------------------------------------------- id 3
__global__ __launch_bounds__(256) void point_gemm_kernel(char* base,
                                                         const float* __restrict__ pc)
{
  BASE(base);
  PROG(3);
  int b = blockIdx.x >> 5; int m0 = (blockIdx.x & 31) * 64;
  int t = threadIdx.x;
  __shared__ __align__(16) float xsm[64 * 68];
  __shared__ float pcs[64 * 4];
  for (int i = t; i < 4096; i += 256) {
    int c = i & 63, mm = i >> 6;
    xsm[mm * 68 + c] = P_XT[((size_t)(b * N_) + m0 + mm) * 64 + c];
  }
  if (t < 192) {
    int mm = t / 3, c = t - mm * 3;
    pcs[mm * 4 + c] = pc[(b * 3 + c) * N_ + m0 + mm];
  }
  __syncthreads();
  int mm = t & 63;
  int og = t >> 6;
  float in[64];
  for (int cq = 0; cq < 16; cq++) {
    float4 v = *(const float4*)&xsm[mm * 68 + cq * 4];
    in[cq * 4 + 0] = v.x; in[cq * 4 + 1] = v.y; in[cq * 4 + 2] = v.z; in[cq * 4 + 3] = v.w;
  }
  int m = m0 + mm;
  {
    float* pp = P_P + ((size_t)(b * N_) + m) * C4_;
    for (int oi = 0; oi < 64; oi++) {
      const float* w = P_WP2 + ((size_t)(og * 64 + oi)) * 64;
      float a = 0.0f;
#pragma unroll
      for (int c = 0; c < 64; c++) a += w[c] * in[c];
      pp[og * 64 + oi] = a;
    }
  }
  if (og < 2) {
    float* sp = P_Sb + ((size_t)(b * N_) + m) * C2_;
    for (int oi = 0; oi < 64; oi++) {
      const float* w = P_WS2 + ((size_t)(og * 64 + oi)) * 64;
      float a = 0.0f;
#pragma unroll
      for (int c = 0; c < 64; c++) a += w[c] * in[c];
      sp[og * 64 + oi] = a;
    }
  }
  if (og == 3) {
    for (int o = 0; o < 16; o++) {
      const float* w = P_WU12 + o * 64;
      float a = 0.0f;
#pragma unroll
      for (int c = 0; c < 64; c++) a += w[c] * in[c];
      P_U1[((b * 16 + o) << 11) + m] = a;
    }
    float* vp = P_V1 + ((size_t)(b * N_) + m) * 16;
    for (int o = 0; o < 16; o++) {
      const float* w = P_WV12 + o * 64;
      float a = 0.0f;
#pragma unroll
      for (int c = 0; c < 64; c++) a += w[c] * in[c];
      vp[o] = a;
    }
  }
  if (og == 2) {
    float p0 = pcs[mm * 4 + 0], p1 = pcs[mm * 4 + 1], p2 = pcs[mm * 4 + 2];
    for (int o = 0; o < 16; o++)
      P_U2[((b * 16 + o) << 11) + m] = P_WU22[o * 4] * p0 + P_WU22[o * 4 + 1] * p1 + P_WU22[o * 4 + 2] * p2;
    float* vp = P_V2 + ((size_t)(b * N_) + m) * 16;
    for (int o = 0; o < 16; o++)
      vp[o] = P_WV22[o * 4] * p0 + P_WV22[o * 4 + 1] * p1 + P_WV22[o * 4 + 2] * p2;
  }
}

// --------------------------------------------------------------------------- id 4
__global__ __launch_bounds__(256) void stats12_kernel(char* base,
    const float* __restrict__ fea_b, const float* __restrict__ xyz_b)
{
  BASE(base);
  PROG(4);
  int b = blockIdx.x >> 5; int n0 = (blockIdx.x & 31) * 64;
  int t = threadIdx.x; int o = t & 15; int kk = t >> 4;
  float fb = fea_b[o], xb = xyz_b[o];
  float s1 = 0, q1 = 0, s2 = 0, q2 = 0;
  for (int nn = 0; nn < 64; nn++) {
    int n = n0 + nn;
    int m = P_IDX[((b << 11) + n) * K_ + kk] & NMASK;
    float a1 = fb + P_U1[((b * 16 + o) << 11) + n] + P_V1[(((size_t)(b << 11) + m) << 4) + o];
    s1 += a1; q1 += a1 * a1;
    float a2 = xb + P_U2[((b * 16 + o) << 11) + n] + P_V2[(((size_t)(b << 11) + m) << 4) + o];
    s2 += a2; q2 += a2 * a2;
  }
  __shared__ float red[256];
  red[t] = s1; __syncthreads();
  if (t < 16) { float s = 0; for (int k2 = 0; k2 < 16; k2++) s += red[k2 * 16 + t]; atomicAdd(&P_ST[ST_S1S + t], s); }
  __syncthreads();
  red[t] = q1; __syncthreads();
  if (t < 16) { float s = 0; for (int k2 = 0; k2 < 16; k2++) s += red[k2 * 16 + t]; atomicAdd(&P_ST[ST_S1Q + t], s); }
  __syncthreads();
  red[t] = s2; __syncthreads();
  if (t < 16) { float s = 0; for (int k2 = 0; k2 < 16; k2++) s += red[k2 * 16 + t]; atomicAdd(&P_ST[ST_S2S + t], s); }
  __syncthreads();
  red[t] = q2; __syncthreads();
  if (t < 16) { float s = 0; for (int k2 = 0; k2 < 16; k2++) s += red[k2 * 16 + t]; atomicAdd(&P_ST[ST_S2Q + t], s); }
}

// --------------------------------------------------------------------------- finalize (ids vary)
__global__ __launch_bounds__(256) void finalize_bn_kernel(char* base,
                                   const float* __restrict__ g,
                                   const float* __restrict__ be,
                                   int sum_off, int sq_off, int sc_off, int sh_off,
                                   int nch, float inv_cnt, int kid)
{
  BASE(base);
  PROG(kid);
  int i = threadIdx.x;
  if (i < nch) {
    float mu = P_ST[sum_off + i] * inv_cnt;
    float var = fmaxf(P_ST[sq_off + i] * inv_cnt - mu * mu, 0.0f);
    float s = g[i] * rsqrtf(var + EPSv);
    P_ST[sc_off + i] = s; P_ST[sh_off + i] = be[i] - mu * s;
  }
}

// --------------------------------------------------------------------------- id 7
__global__ __launch_bounds__(256) void w1_kernel(char* base,
    const float* __restrict__ fea_b, const float* __restrict__ xyz_b)
{
  BASE(base);
  PROG(7);
  int gid = blockIdx.x * 256 + threadIdx.x;    // 262144
  int n = gid & 2047; int c = (gid >> 11) & 15; int b = gid >> 15;
  const int* ip = P_IDX + ((size_t)((b << 11) + n)) * 16;
  float u1 = P_U1[((b * 16 + c) << 11) + n];
  float u2 = P_U2[((b * 16 + c) << 11) + n];
  float c1 = fea_b[c] + u1, c2v = xyz_b[c] + u2;
  float s1 = P_ST[ST_B1SC + c], h1 = P_ST[ST_B1SH + c];
  float s2 = P_ST[ST_B2SC + c], h2 = P_ST[ST_B2SH + c];
  float o16[16];
#pragma unroll
  for (int kk = 0; kk < 16; kk++) {
    int m = ip[kk] & NMASK;
    float a1 = c1 + P_V1[(((size_t)(b << 11) + m) << 4) + c];
    a1 = lrelu(a1 * s1 + h1);
    float a2 = c2v + P_V2[(((size_t)(b << 11) + m) << 4) + c];
    a2 = lrelu(a2 * s2 + h2);
    o16[kk] = a1 * a2;
  }
  float* wp = P_W1 + ((size_t)(b * 16 + c)) * NK_ + ((size_t)n << 4);
#pragma unroll
  for (int j = 0; j < 4; j++)
    *(float4*)(wp + j * 4) = make_float4(o16[4 * j], o16[4 * j + 1], o16[4 * j + 2], o16[4 * j + 3]);
}

// --------------------------------------------------------------------------- id 8
__global__ __launch_bounds__(256) void stats3_kernel(char* base)
{
  BASE(base);
  PROG(8);
  int b = blockIdx.x >> 5; int col0 = (blockIdx.x & 31) * 1024;
  int t = threadIdx.x;
  __shared__ float sw[16 * 129];
  int c1 = 0, rem = t;
  if (t < 136) {
    while (rem >= 16 - c1) { rem -= 16 - c1; c1++; }
  }
  int c2 = c1 + rem;
  float acc = 0.0f;
  for (int ck = 0; ck < 8; ck++) {
    __syncthreads();
    for (int i = t; i < 2048; i += 256) {
      int c = i >> 7, l = i & 127;
      sw[c * 129 + l] = P_W1[((size_t)(b * 16 + c)) * NK_ + col0 + ck * 128 + l];
    }
    __syncthreads();
    if (t < 136) {
      const float* r1 = sw + c1 * 129;
      const float* r2 = sw + c2 * 129;
      for (int l = 0; l < 128; l++) acc += r1[l] * r2[l];
    } else if (t < 152) {
      const float* r = sw + (t - 136) * 129;
      for (int l = 0; l < 128; l++) acc += r[l];
    }
  }
  if (t < 136) atomicAdd(&P_ST[ST_S3M + t], acc);
  else if (t < 152) atomicAdd(&P_ST[ST_S3V + t - 136], acc);
}

// --------------------------------------------------------------------------- id 9
__global__ __launch_bounds__(256) void finalize_bn3_kernel(char* base,
                                    const float* __restrict__ b1,
                                    const float* __restrict__ g,
                                    const float* __restrict__ be)
{
  BASE(base);
  PROG(9);
  int o = threadIdx.x;
  if (o >= 64) return;
  float A[16];
  for (int c = 0; c < 16; c++) A[c] = P_A12[o * 16 + c];
  float dv = 0.0f;
  for (int c = 0; c < 16; c++) dv += A[c] * P_ST[ST_S3V + c];
  float quad = 0.0f; int p = 0;
  for (int c1 = 0; c1 < 16; c1++)
    for (int c2 = c1; c2 < 16; c2++) {
      float m = P_ST[ST_S3M + p]; p++;
      quad += (c1 == c2 ? 1.0f : 2.0f) * A[c1] * A[c2] * m;
    }
  float bo = b1[o];
  const float inv = 1.0f / 262144.0f;
  float mean = dv * inv + bo;
  float e2 = quad * inv + 2.0f * bo * dv * inv + bo * bo;
  float var = fmaxf(e2 - mean * mean, 0.0f);
  float s = g[o] * rsqrtf(var + EPSv);
  P_ST[ST_B3SC + o] = s; P_ST[ST_B3SH + o] = be[o] - mean * s;
}

// --------------------------------------------------------------------------- id 10
// a4 -> A4 bf16 [b][n][cc*16+kk]
__global__ __launch_bounds__(256) void a4_kernel(char* base,
                                                 const float* __restrict__ all1_b,
                                                 const float* __restrict__ all2_b)
{
  BASE(base);
  PROG(10);
  int b = blockIdx.x >> 7; int col0 = (blockIdx.x & 127) * 256;
  int t = threadIdx.x;
  __shared__ float sw[16 * 256];
  for (int i = t; i < 16 * 256; i += 256) {
    int c = i >> 8, cc = i & 255;
    sw[i] = P_W1[((size_t)(b * 16 + c)) * NK_ + col0 + cc];
  }
  __syncthreads();
  float in[16];
  for (int c = 0; c < 16; c++) in[c] = sw[c * 256 + t];
  float h[64];
  for (int o = 0; o < 64; o++) {
    const float* wr = P_A12 + o * 16;
    float a = all1_b[o];
#pragma unroll
    for (int c = 0; c < 16; c++) a += wr[c] * in[c];
    h[o] = lrelu(a * P_ST[ST_B3SC + o] + P_ST[ST_B3SH + o]);
  }
  int col = col0 + t; int n = col >> 4; int kk = col & 15;
  ushort_t* dst = P_A4 + ((size_t)(b * N_) + n) * 2048 + kk;
  for (int o = 0; o < 128; o++) {
    const float* wr = P_A22 + o * 64;
    float a = all2_b[o];
#pragma unroll
    for (int c = 0; c < 64; c++) a += wr[c] * h[c];
    dst[o * 16] = f2bf(a);
  }
}

// --------------------------------------------------------------------------- id 11
__global__ __launch_bounds__(256) void stats4_kernel(char* base)
{
  BASE(base);
  PROG(11);
  int cc = blockIdx.x & 127; int ch = blockIdx.x >> 7;   // 32 chunks
  int r0 = ch * 512;
  float s = 0, q = 0;
  for (int rr = threadIdx.x; rr < 512; rr += 256) {
    const ushort_t* p = P_A4 + (size_t)(r0 + rr) * 2048 + cc * 16;
    uint4 u0 = *(const uint4*)p;
    uint4 u1 = *(const uint4*)(p + 8);
    unsigned ws[8] = {u0.x, u0.y, u0.z, u0.w, u1.x, u1.y, u1.z, u1.w};
#pragma unroll
    for (int j = 0; j < 8; j++) {
      float lo = bf2f(ws[j] << 16 >> 16 << 16 >> 16);   // placeholder avoided below
      (void)lo;
    }
#pragma unroll
    for (int j = 0; j < 8; j++) {
      float v0 = bf2f((ws[j] & 0xffffu) << 16 >> 16);    // not used
      (void)v0;
    }
#pragma unroll
    for (int j = 0; j < 8; j++) {
      union { float f; unsigned u; } a, bvu;
      a.u = ws[j] << 16; bvu.u = ws[j] & 0xffff0000u;
      s += a.f + bvu.f; q += a.f * a.f + bvu.f * bvu.f;
    }
  }
  __shared__ float rs[256], rq[256];
  int t = threadIdx.x;
  rs[t] = s; rq[t] = q; __syncthreads();
  for (int st = 128; st > 0; st >>= 1) {
    if (t < st) { rs[t] += rs[t + st]; rq[t] += rq[t + st]; }
    __syncthreads();
  }
  if (t == 0) { atomicAdd(&P_ST[ST_S4S + cc], rs[0]); atomicAdd(&P_ST[ST_S4Q + cc], rq[0]); }
}

// --------------------------------------------------------------------------- id 13
__global__ __launch_bounds__(256) void softmax_kernel(char* base)
{
  BASE(base);
  PROG(13);
  int rid = blockIdx.x * 256 + threadIdx.x;   // 2,097,152
  int cc = rid & 127; int r = rid >> 7;
  float s = P_ST[ST_B4SC + cc], h = P_ST[ST_B4SH + cc];
  ushort_t* p = P_A4 + (size_t)r * 2048 + cc * 16;
  uint4 u0 = *(const uint4*)p;
  uint4 u1 = *(const uint4*)(p + 8);
  unsigned ws[8] = {u0.x, u0.y, u0.z, u0.w, u1.x, u1.y, u1.z, u1.w};
  float v[16];
#pragma unroll
  for (int j = 0; j < 8; j++) {
    union { float f; unsigned u; } lo, hi;
    lo.u = ws[j] << 16; hi.u = ws[j] & 0xffff0000u;
    v[2 * j] = lo.f; v[2 * j + 1] = hi.f;
  }
  float mx = -BIGF;
#pragma unroll
  for (int i = 0; i < 16; i++) {
    float y = lrelu(v[i] * s + h);
    v[i] = y; mx = fmaxf(mx, y);
  }
  float sum = 0.0f;
#pragma unroll
  for (int i = 0; i < 16; i++) { float e = expf(v[i] - mx); v[i] = e; sum += e; }
  float inv = (sum > 0.0f) ? 1.0f / sum : 0.0f;
#pragma unroll
  for (int j = 0; j < 8; j++)
    ws[j] = (unsigned)f2bf(v[2 * j] * inv) | ((unsigned)f2bf(v[2 * j + 1] * inv) << 16);
  *(uint4*)p = make_uint4(ws[0], ws[1], ws[2], ws[3]);
  *(uint4*)(p + 8) = make_uint4(ws[4], ws[5], ws[6], ws[7]);
}

// --------------------------------------------------------------------------- id 14
__global__ __launch_bounds__(256) void qgemm_kernel(char* base)
{
  BASE(base);
  PROG(14);
  int b = blockIdx.x >> 8; int r = blockIdx.x & 255;
  int osp = r & 7; int m0 = (r >> 3) * 64;
  int t = threadIdx.x;
  __shared__ __align__(16) float xsm[64 * 68];
  for (int i = t; i < 4096; i += 256) {
    int c = i & 63, mm = i >> 6;
    xsm[mm * 68 + c] = P_XT[((size_t)(b * N_) + m0 + mm) * 64 + c];
  }
  __syncthreads();
  int mm = t & 63;
  int og = t >> 6;
  float in[64];
  for (int cq = 0; cq < 16; cq++) {
    float4 v = *(const float4*)&xsm[mm * 68 + cq * 4];
    in[cq * 4 + 0] = v.x; in[cq * 4 + 1] = v.y; in[cq * 4 + 2] = v.z; in[cq * 4 + 3] = v.w;
  }
  int m = m0 + mm;
  int obase = osp * 32 + og * 8;
  for (int t9 = 0; t9 < TAP_; t9++) {
    ushort_t* qp = P_QB + ((size_t)(b * N_ + m) * TAP_ + t9) * C4_ + obase;
    const float* wq = P_WQ2 + ((size_t)(t9 * 256 + obase)) * 64;
    for (int oi = 0; oi < 8; oi++) {
      const float* w = wq + oi * 64;
      float a = 0.0f;
#pragma unroll
      for (int c = 0; c < 64; c++) a += w[c] * in[c];
      qp[oi] = f2bf(a);
    }
  }
}

// --------------------------------------------------------------------------- id 15
__global__ __launch_bounds__(256) void inte_fused_kernel(char* base,
                                                         const float* __restrict__ inte_b)
{
  BASE(base);
  PROG(15);
  int b = blockIdx.x >> 9; int n0 = (blockIdx.x & 511) * 4;
  int t = threadIdx.x; int o = t;
  __shared__ int sidx[4][16];
  if (t < 64) sidx[t >> 4][t & 15] = P_IDX[((size_t)(b * N_) + n0 + (t >> 4)) * K_ + (t & 15)] & NMASK;
  __syncthreads();
  float bias = inte_b[o];
  float ssum = 0.0f, ssq = 0.0f;
  for (int nn = 0; nn < 4; nn++) {
    int n = n0 + nn;
    float bse = bias + P_P[((size_t)(b * N_) + n) * C4_ + o];
    float acc[8];
#pragma unroll
    for (int j = 0; j < 8; j++) acc[j] = bse;
    for (int p = 0; p < 16; p++) {
      const ushort_t* qr = P_QB + (size_t)(b * N_ + sidx[nn][p]) * TAP_ * C4_ + o;
#pragma unroll
      for (int tt = 0; tt < TAP_; tt++) {
        int j = p - tt;
        if (j >= 0 && j < 8) acc[j] += bf2f(((unsigned)qr[tt * C4_]) << 16 >> 16 << 16 >> 16);
      }
    }
    ushort_t* ip = P_IT + ((size_t)(b * N_) + n) * 2048 + o * 8;
#pragma unroll
    for (int j = 0; j < 8; j++) { float v = acc[j]; ip[j] = f2bf(v); ssum += v; ssq += v * v; }
  }
  atomicAdd(&P_ST[ST_S5S + o], ssum);
  atomicAdd(&P_ST[ST_S5Q + o], ssq);
}

// --------------------------------------------------------------------------- id 21
// M = lrelu(bn5(IT)) * A4  -> bf16, flat index
__global__ __launch_bounds__(256) void fuse_kernel(char* base)
{
  BASE(base);
  PROG(21);
  __shared__ float sc5s[256], sh5s[256];
  if (threadIdx.x < 256) { sc5s[threadIdx.x] = P_ST[ST_B5SC + threadIdx.x]; sh5s[threadIdx.x] = P_ST[ST_B5SH + threadIdx.x]; }
  __syncthreads();
  size_t g8 = ((size_t)blockIdx.x * 256 + threadIdx.x) * 8;   // 8-aligned within row
  int o5 = (int)((g8 & 2047) >> 3);
  float s5 = sc5s[o5], h5 = sh5s[o5];
  const ushort_t* itp = P_IT + g8;
  const ushort_t* a4p = P_A4 + g8;
  uint4 iu = *(const uint4*)itp;
  uint4 au = *(const uint4*)a4p;
  unsigned iw[4] = {iu.x, iu.y, iu.z, iu.w};
  unsigned aw[4] = {au.x, au.y, au.z, au.w};
  unsigned mw[4];
#pragma unroll
  for (int j = 0; j < 4; j++) {
    union { float f; unsigned u; } il, ih, al, ah;
    il.u = iw[j] << 16; ih.u = iw[j] & 0xffff0000u;
    al.u = aw[j] << 16; ah.u = aw[j] & 0xffff0000u;
    float m0 = lrelu(il.f * s5 + h5) * al.f;
    float m1 = lrelu(ih.f * s5 + h5) * ah.f;
    mw[j] = (unsigned)f2bf(m0) | ((unsigned)f2bf(m1) << 16);
  }
  *(uint4*)(P_M + g8) = make_uint4(mw[0], mw[1], mw[2], mw[3]);
}

// --------------------------------------------------------------------------- id 17
// final conv v5: merged part reads bf16 M (contiguous); k-split x2.
__global__ __launch_bounds__(256) void final_conv_kernel(char* base)
{
  BASE(base);
  PROG(17);
  int ks = blockIdx.x & 1; int g = (blockIdx.x >> 1) & 1;
  int tile = (blockIdx.x >> 2) & 31; int b = blockIdx.x >> 7;
  int n0 = tile * 64;
  int t = threadIdx.x;
  int col = t & 63;
  int osec = t >> 6;
  int obase = g * 64 + osec * 16;
  __shared__ float tileS[128 * 65];
  __shared__ int sidxT[16 * 64];        // [p][cl]
  for (int i = t; i < 1024; i += 256) {
    int cl = i & 63, p = i >> 6;
    sidxT[p * 64 + cl] = P_IDX[((size_t)(b * N_) + n0 + cl) * K_ + p] & NMASK;
  }
  float acc[16];
#pragma unroll
  for (int oi = 0; oi < 16; oi++) acc[oi] = 0.0f;
  int kbeg = ks * 1536;
  for (int k0 = kbeg; k0 < kbeg + 1536; k0 += 128) {
    __syncthreads();
    if (k0 < 1024) {
      int c0 = k0 >> 4;
      int cl = t & 63; int pg = t >> 6;
      for (int pp = 0; pp < 4; pp++) {
        int p = pg * 4 + pp;
        int m = sidxT[p * 64 + cl];
        const float* xp = P_XT + ((size_t)(b * N_) + m) * 64 + c0;
        float4 v0 = *(const float4*)xp;
        float4 v1 = *(const float4*)(xp + 4);
        tileS[(0 * 16 + p) * 65 + cl] = v0.x;
        tileS[(1 * 16 + p) * 65 + cl] = v0.y;
        tileS[(2 * 16 + p) * 65 + cl] = v0.z;
        tileS[(3 * 16 + p) * 65 + cl] = v0.w;
        tileS[(4 * 16 + p) * 65 + cl] = v1.x;
        tileS[(5 * 16 + p) * 65 + cl] = v1.y;
        tileS[(6 * 16 + p) * 65 + cl] = v1.z;
        tileS[(7 * 16 + p) * 65 + cl] = v1.w;
      }
    } else {
      int cl = t & 63; int kg = t >> 6;           // 4 groups x 32 k
      size_t rb = ((size_t)(b * N_) + n0 + cl) * 2048 + (size_t)(k0 - 1024) + kg * 32;
      const ushort_t* mp = P_M + rb;
      for (int j8 = 0; j8 < 4; j8++) {
        uint4 u = *(const uint4*)(mp + j8 * 8);
        unsigned ws[4] = {u.x, u.y, u.z, u.w};
#pragma unroll
        for (int q = 0; q < 4; q++) {
          union { float f; unsigned uu; } lo, hi;
          lo.uu = ws[q] << 16; hi.uu = ws[q] & 0xffff0000u;
          int kc = kg * 32 + j8 * 8 + q * 2;
          tileS[kc * 65 + cl] = lo.f;
          tileS[(kc + 1) * 65 + cl] = hi.f;
        }
      }
    }
    __syncthreads();
    for (int kc = 0; kc < 128; kc++) {
      float v = tileS[kc * 65 + col];
      const float* wr = P_WC2 + (size_t)(k0 + kc) * C2_ + obase;
#pragma unroll
      for (int oi = 0; oi < 16; oi++) acc[oi] += wr[oi] * v;
    }
  }
  float* op = P_PART + ((size_t)ks * B_ * N_ + (size_t)b * N_ + n0 + col) * C2_ + obase;
#pragma unroll
  for (int oi = 0; oi < 16; oi++) op[oi] = acc[oi];
}

// --------------------------------------------------------------------------- id 18
__global__ __launch_bounds__(256) void reduce_stats_kernel(char* base,
                                                           const float* __restrict__ c2_b)
{
  BASE(base);
  PROG(18);
  int r0 = blockIdx.x * 128;    // grid 128
  int t = threadIdx.x; int o = t & 127; int h = t >> 7;
  const size_t STRIDE = (size_t)B_ * N_ * C2_;
  float cb = c2_b[o];
  float s = 0, q = 0;
  for (int r = r0 + h; r < r0 + 128; r += 2) {
    size_t off = (size_t)r * C2_ + o;
    float v = cb + P_Sb[off] + P_PART[off] + P_PART[STRIDE + off];
    P_OUT2[off] = v;
    s += v; q += v * v;
  }
  __shared__ float rs[256], rq[256];
  rs[t] = s; rq[t] = q; __syncthreads();
  if (t < 128) {
    atomicAdd(&P_ST[ST_S6S + o], rs[t] + rs[t + 128]);
    atomicAdd(&P_ST[ST_S6Q + o], rq[t] + rq[t + 128]);
  }
}

// --------------------------------------------------------------------------- id 20
__global__ __launch_bounds__(256) void output_kernel(char* base, float* __restrict__ out)
{
  BASE(base);
  PROG(20);
  int i = blockIdx.x * 256 + threadIdx.x;
  int j = i & 4095; int f = (i >> 12) & 63; int b = i >> 18;
  int o = 2 * f + (j >> 11); int n = j & 2047;
  float v = P_OUT2[((size_t)(b * N_) + n) * C2_ + o];
  v = v * P_ST[ST_B6SC + o] + P_ST[ST_B6SH + o];
  out[i] = fmaxf(v, 0.0f);
}

// --------------------------------------------------------------------------- diagnostics
__global__ void diag_kernel(char* base, float* __restrict__ out)
{
  BASE(base);
  const int expctd[22] = {1, 6349, 4096, 256, 256, 1, 1, 1024, 256, 1, 1024,
                          4096, 1, 8192, 2048, 4096, 1, 1024, 128, 1, 8192, 16384};
  int t = threadIdx.x;
  int bad = 99;
  if (t < 22 && P_PROG[t] != expctd[t]) bad = t;
#pragma unroll
  for (int off = 32; off > 0; off >>= 1) {
    int ob = __shfl_xor(bad, off);
    if (ob < bad) bad = ob;
  }
  if (t == 0 && bad != 99) out[0] = 100.0f + 10.0f * (float)bad;
}

__global__ void code_kernel(float* __restrict__ out, float code)
{
  if (threadIdx.x == 0 && blockIdx.x == 0) out[0] = code;
}

// ---------------------------------------------------------------------------
extern "C" void kernel_launch(void* const* d_in, const int* in_sizes, int n_in,
                              void* d_out, int out_size, void* d_ws, size_t ws_size,
                              hipStream_t stream) {
  const float* x      = (const float*)d_in[0];
  const float* pc     = (const float*)d_in[1];
  const float* fea_w  = (const float*)d_in[2];
  const float* fea_b  = (const float*)d_in[3];
  const float* fea_g  = (const float*)d_in[4];
  const float* fea_be = (const float*)d_in[5];
  const float* xyz_w  = (const float*)d_in[6];
  const float* xyz_b  = (const float*)d_in[7];
  const float* xyz_g  = (const float*)d_in[8];
  const float* xyz_be = (const float*)d_in[9];
  const float* all1_w = (const float*)d_in[10];
  const float* all1_b = (const float*)d_in[11];
  const float* all1_g = (const float*)d_in[12];
  const float* all1_be= (const float*)d_in[13];
  const float* all2_w = (const float*)d_in[14];
  const float* all2_b = (const float*)d_in[15];
  const float* all2_g = (const float*)d_in[16];
  const float* all2_be= (const float*)d_in[17];
  const float* inte_w = (const float*)d_in[18];
  const float* inte_b = (const float*)d_in[19];
  const float* inte_g = (const float*)d_in[20];
  const float* inte_be= (const float*)d_in[21];
  const float* c2_w   = (const float*)d_in[22];
  const float* c2_b   = (const float*)d_in[23];
  const float* c2_g   = (const float*)d_in[24];
  const float* c2_be  = (const float*)d_in[25];
  float* out = (float*)d_out;
  (void)in_sizes; (void)n_in; (void)out_size; (void)d_ws; (void)ws_size;

  if (g_pool_mem == nullptr) {
    code_kernel<<<1, 64, 0, stream>>>(out, 500.0f);
    return;
  }
  char* base = g_pool_mem;

  zero_kernel<<<1, 256, 0, stream>>>(base);
  prep_kernel<<<6349, 256, 0, stream>>>(base, x, fea_w, xyz_w, inte_w, c2_w, all1_w, all2_w);
  knn_kernel<<<4096, 256, 0, stream>>>(base);
  point_gemm_kernel<<<256, 256, 0, stream>>>(base, pc);
  stats12_kernel<<<256, 256, 0, stream>>>(base, fea_b, xyz_b);
  finalize_bn_kernel<<<1, 256, 0, stream>>>(base, fea_g, fea_be, ST_S1S, ST_S1Q, ST_B1SC, ST_B1SH, 16, 1.0f / 262144.0f, 5);
  finalize_bn_kernel<<<1, 256, 0, stream>>>(base, xyz_g, xyz_be, ST_S2S, ST_S2Q, ST_B2SC, ST_B2SH, 16, 1.0f / 262144.0f, 6);
  w1_kernel<<<1024, 256, 0, stream>>>(base, fea_b, xyz_b);
  stats3_kernel<<<256, 256, 0, stream>>>(base);
  finalize_bn3_kernel<<<1, 256, 0, stream>>>(base, all1_b, all1_g, all1_be);
  a4_kernel<<<1024, 256, 0, stream>>>(base, all1_b, all2_b);
  stats4_kernel<<<4096, 256, 0, stream>>>(base);
  finalize_bn_kernel<<<1, 256, 0, stream>>>(base, all2_g, all2_be, ST_S4S, ST_S4Q, ST_B4SC, ST_B4SH, 128, 1.0f / 262144.0f, 12);
  softmax_kernel<<<8192, 256, 0, stream>>>(base);
  qgemm_kernel<<<2048, 256, 0, stream>>>(base);
  inte_fused_kernel<<<4096, 256, 0, stream>>>(base, inte_b);
  finalize_bn_kernel<<<1, 256, 0, stream>>>(base, inte_g, inte_be, ST_S5S, ST_S5Q, ST_B5SC, ST_B5SH, 256, 1.0f / 131072.0f, 16);
  fuse_kernel<<<16384, 256, 0, stream>>>(base);
  final_conv_kernel<<<1024, 256, 0, stream>>>(base);
  reduce_stats_kernel<<<128, 256, 0, stream>>>(base, c2_b);
  finalize_bn_kernel<<<1, 256, 0, stream>>>(base, c2_g, c2_be, ST_S6S, ST_S6Q, ST_B6SC, ST_B6SH, 128, 1.0f / 16384.0f, 19);
  output_kernel<<<8192, 256, 0, stream>>>(base, out);
  diag_kernel<<<1, 64, 0, stream>>>(base, out);
}